// Round 1
// baseline (138.506 us; speedup 1.0000x reference)
//
#include <hip/hip_runtime.h>
#include <hip/hip_bf16.h>

// RewardHead fused kernel for MI355X (gfx950).
// B=32768 rows, D=64, A=32, K=16, M=128. Output: [B,1] f32.
//
// d_ws layout: [0, 256KB): packed bf16 MFMA B-fragments for all weights
//              [256KB, +8): {1/(sigma_form+1e-6), 1/(sigma_cons+1e-6)}

typedef float f32x4 __attribute__((ext_vector_type(4)));
typedef short s16x8 __attribute__((ext_vector_type(8)));

#define OFF_ACTX 0
#define OFF_CTLX 24
#define OFF_CHTX 56
#define OFF_ACTZ 80
#define OFF_CTLZ 84
#define OFF_CHTZ 92
#define OFF_WE   96
#define OFF_WQ   112
#define OFF_WK   144
#define OFF_WV   176
#define OFF_WO   208
#define OFF_FORM 240
#define N_TILES  256
#define SIG_OFF  (N_TILES*1024)   // bytes into d_ws

__device__ __forceinline__ unsigned short f2bf(float f){
  unsigned u = __float_as_uint(f);
  u += 0x7fffu + ((u>>16)&1u);          // RNE
  return (unsigned short)(u>>16);
}

union V8 { s16x8 v; unsigned short us[8]; uint4 q; };

__device__ __forceinline__ f32x4 MF(s16x8 a, s16x8 b, f32x4 c){
  return __builtin_amdgcn_mfma_f32_16x16x32_bf16(a, b, c, 0, 0, 0);
}

// B-fragment: one 16B load per lane from pre-packed tiles.
__device__ __forceinline__ s16x8 ldB(const unsigned short* __restrict__ pk, int tile, int lane){
  V8 t;
  t.q = *reinterpret_cast<const uint4*>(pk + (((size_t)tile<<6) + lane)*8);
  return t.v;
}

// A-fragment from global f32 row data: 8 consecutive dims starting at ko,
// zero-filled when ko >= limit (K padding; also prevents OOB on last row).
__device__ __forceinline__ s16x8 ldA_g(const float* __restrict__ p, int ko, int limit){
  V8 t;
  if (ko < limit){
    const float4* q4 = reinterpret_cast<const float4*>(p + ko);
    float4 a = q4[0], b = q4[1];
    t.us[0]=f2bf(a.x); t.us[1]=f2bf(a.y); t.us[2]=f2bf(a.z); t.us[3]=f2bf(a.w);
    t.us[4]=f2bf(b.x); t.us[5]=f2bf(b.y); t.us[6]=f2bf(b.z); t.us[7]=f2bf(b.w);
  } else {
    t.q = make_uint4(0u,0u,0u,0u);
  }
  return t.v;
}

// A-fragment from a 16x128 bf16 LDS tile with XOR swizzle (byte ^= (row&7)<<4).
__device__ __forceinline__ s16x8 ldA_l(const unsigned short* buf, int lane, int kt){
  int row = lane & 15;
  int bo = (row<<8) + (kt<<6) + ((lane>>4)<<4);
  bo ^= (row & 7) << 4;
  return *reinterpret_cast<const s16x8*>(buf + (bo>>1));
}

// Store one D-tile column-slice (4 rows) to swizzled LDS as bf16.
__device__ __forceinline__ void stD(unsigned short* buf, int lane, int nt, f32x4 v){
  int colb = (((nt<<4) + (lane&15))<<1);
  int rb = (lane>>4)<<2;
  #pragma unroll
  for (int j=0;j<4;++j){
    int row = rb + j;
    int bo = ((row<<8) + colb) ^ ((row&7)<<4);
    buf[bo>>1] = f2bf(v[j]);
  }
}

__device__ __forceinline__ float tanh_fast(float x){
  x = fminf(15.f, fmaxf(-15.f, x));
  float e = __expf(2.f*x);
  return 1.f - __fdividef(2.f, e + 1.f);
}

// ---------------- weight pre-pack ----------------
// One block per tile (256 tiles), 512 threads: element (lane, i) of the tile.
// Packed element = W[srcrow(k)][n], k = kt*32 + (lane>>4)*8 + i, n = nt*16 + (lane&15).
__global__ __launch_bounds__(512) void pack_k(
    const float* __restrict__ aWx, const float* __restrict__ cWx, const float* __restrict__ hWx,
    const float* __restrict__ aWz, const float* __restrict__ cWz, const float* __restrict__ hWz,
    const float* __restrict__ We,  const float* __restrict__ Wq,  const float* __restrict__ Wk,
    const float* __restrict__ Wv,  const float* __restrict__ Wo,  const float* __restrict__ fW,
    unsigned short* __restrict__ packed)
{
  int tile = blockIdx.x;
  const float* W; int N; int kind = 0; int base;
  if      (tile < 24) { W=aWx; N=128; base=OFF_ACTX; }
  else if (tile < 56) { W=cWx; N=128; base=OFF_CTLX; }
  else if (tile < 80) { W=hWx; N=128; base=OFF_CHTX; kind=1; }  // rows: 0-15 rw, pad 16-31, 32-95 -> z rows 16-79
  else if (tile < 84) { W=aWz; N=64;  base=OFF_ACTZ; }
  else if (tile < 92) { W=cWz; N=64;  base=OFF_CTLZ; }
  else if (tile < 96) { W=hWz; N=64;  base=OFF_CHTZ; kind=2; }  // rows 0-15 real, 16-31 pad
  else if (tile < 112){ W=We;  N=128; base=OFF_WE; }
  else if (tile < 144){ W=Wq;  N=128; base=OFF_WQ; }
  else if (tile < 176){ W=Wk;  N=128; base=OFF_WK; }
  else if (tile < 208){ W=Wv;  N=128; base=OFF_WV; }
  else if (tile < 240){ W=Wo;  N=128; base=OFF_WO; }
  else                { W=fW;  N=64;  base=OFF_FORM; }
  int NT = N >> 4;
  int lt = tile - base;
  int nt = lt % NT, kt = lt / NT;
  int tid = threadIdx.x;
  int lane = tid >> 3, i = tid & 7;
  int k = kt*32 + ((lane>>4)<<3) + i;
  int n = nt*16 + (lane & 15);
  int sr = k;
  if (kind == 1) sr = (k < 16) ? k : (k < 32 ? -1 : k - 16);
  else if (kind == 2) sr = (k < 16) ? k : -1;
  float v = (sr >= 0) ? W[(size_t)sr*N + n] : 0.f;
  packed[(((size_t)tile<<6) + lane)*8 + i] = f2bf(v);
}

// ---------------- spectral norms ----------------
// sigma(form_W) via power iteration on G^16 (G = W^T W, squared 4x),
// sigma(cons_W) = vector 2-norm. Writes inverse scales to sig[0..1].
__global__ __launch_bounds__(256) void sigma_k(
    const float* __restrict__ formW, const float* __restrict__ consW,
    float* __restrict__ sig)
{
  __shared__ float Wl[128][65];
  __shared__ float Ga[64][65];
  __shared__ float Gb[64][65];
  __shared__ float xv[64];
  int tid = threadIdx.x;
  for (int idx = tid; idx < 128*64; idx += 256) Wl[idx>>6][idx&63] = formW[idx];
  __syncthreads();
  for (int idx = tid; idx < 64*64; idx += 256){
    int i = idx>>6, j = idx&63;
    float s = 0.f;
    for (int m = 0; m < 128; ++m) s += Wl[m][i]*Wl[m][j];
    Ga[i][j] = s;
  }
  __syncthreads();
  for (int sq = 0; sq < 4; ++sq){           // G -> G^2 -> G^4 -> G^8 -> G^16 (ends in Ga)
    float (*S)[65] = (sq & 1) ? Gb : Ga;
    float (*D)[65] = (sq & 1) ? Ga : Gb;
    for (int idx = tid; idx < 64*64; idx += 256){
      int i = idx>>6, j = idx&63;
      float s = 0.f;
      #pragma unroll 8
      for (int m = 0; m < 64; ++m) s += S[i][m]*S[m][j];
      D[i][j] = s;
    }
    __syncthreads();
  }
  // wave 0 only: normalized power iteration, all in-wave (no barriers needed).
  if (tid < 64){
    xv[tid] = 1.f + 0.5f*__sinf(1.7f*(float)tid);
    float lam = 1.f;
    for (int it = 0; it < 48; ++it){
      float y = 0.f;
      for (int m = 0; m < 64; ++m) y += Ga[tid][m]*xv[m];
      float ss = y*y;
      #pragma unroll
      for (int msk = 1; msk < 64; msk <<= 1) ss += __shfl_xor(ss, msk);
      lam = ss;                              // ||G16 x||^2 with ||x||=1 (it>=1)
      xv[tid] = y * rsqrtf(ss);
    }
    if (tid == 0){
      float lam16 = sqrtf(lam);              // lambda_max(G^16) = sigma^32
      float sf = exp2f(log2f(lam16)*(1.f/32.f));
      float sc2 = 0.f;
      for (int i2 = 0; i2 < 128; ++i2){ float c = consW[i2]; sc2 += c*c; }
      sig[0] = 1.f/(sf + 1e-6f);
      sig[1] = 1.f/(sqrtf(sc2) + 1e-6f);
    }
  }
}

// ---------------- tokenizer stage (per wave) ----------------
template<int KTX, int KTZ>
__device__ __forceinline__ void token_stage(
    const unsigned short* __restrict__ pk, int offX, const s16x8* afX,
    int offZ, const s16x8* afZ, const float* __restrict__ bx,
    unsigned short* Xdst, float* ScT, int lane)
{
  const int r15 = lane & 15, rb = (lane>>4)<<2;
  const f32x4 z4 = {0.f,0.f,0.f,0.f};
  f32x4 acc[8];
  #pragma unroll
  for (int nt = 0; nt < 8; ++nt) acc[nt] = z4;
  #pragma unroll
  for (int kt = 0; kt < KTX; ++kt){
    #pragma unroll
    for (int nt = 0; nt < 8; ++nt)
      acc[nt] = MF(afX[kt], ldB(pk, offX + kt*8 + nt, lane), acc[nt]);
  }
  #pragma unroll
  for (int nt = 0; nt < 8; ++nt){
    float bv = bx[nt*16 + r15];
    f32x4 v;
    #pragma unroll
    for (int j = 0; j < 4; ++j) v[j] = tanh_fast(acc[nt][j] + bv);
    stD(Xdst, lane, nt, v);
  }
  // dist2 = || tanh(u @ Wz) ||^2  (z_t itself is never needed)
  f32x4 a2[4];
  #pragma unroll
  for (int nt = 0; nt < 4; ++nt) a2[nt] = z4;
  #pragma unroll
  for (int kt = 0; kt < KTZ; ++kt){
    #pragma unroll
    for (int nt = 0; nt < 4; ++nt)
      a2[nt] = MF(afZ[kt], ldB(pk, offZ + kt*4 + nt, lane), a2[nt]);
  }
  float d2[4];
  #pragma unroll
  for (int j = 0; j < 4; ++j){
    float s = 0.f;
    #pragma unroll
    for (int nt = 0; nt < 4; ++nt){ float t = tanh_fast(a2[nt][j]); s += t*t; }
    d2[j] = s;
  }
  #pragma unroll
  for (int m = 1; m < 16; m <<= 1){
    #pragma unroll
    for (int j = 0; j < 4; ++j) d2[j] += __shfl_xor(d2[j], m);
  }
  if (r15 == 0){
    #pragma unroll
    for (int j = 0; j < 4; ++j) ScT[rb+j] = -d2[j];
  }
}

// ---------------- main fused kernel ----------------
// 4 waves/block, each wave owns 16 rows end-to-end; no inter-wave sync.
__global__ __launch_bounds__(256) void reward_main(
    const float* __restrict__ z, const float* __restrict__ action,
    const float* __restrict__ rw, const float* __restrict__ control,
    const float* __restrict__ act_bx, const float* __restrict__ ctl_bx,
    const float* __restrict__ cht_bx, const float* __restrict__ be,
    const float* __restrict__ consW, const float* __restrict__ consb,
    const float* __restrict__ formb,
    const unsigned short* __restrict__ packed, const float* __restrict__ sig,
    float* __restrict__ out)
{
  __shared__ unsigned short sX[4][3][2048];   // per-wave token features (bf16, swizzled)
  __shared__ unsigned short sBuf[4][2048];    // per-wave scratch (xq / feat_pre / feat)
  __shared__ float sSc[4][3][16];             // per-wave scores -> attn

  const int wid  = threadIdx.x >> 6;
  const int lane = threadIdx.x & 63;
  const int g0   = blockIdx.x*64 + wid*16;
  const int r15  = lane & 15;
  const int hi   = lane >> 4;
  const int ko   = hi << 3;
  const int rb   = hi << 2;
  const int arow = g0 + r15;

  unsigned short* Bu = sBuf[wid];
  float (*Sc)[16] = sSc[wid];
  const f32x4 z4 = {0.f,0.f,0.f,0.f};

  // ---- raw-input A-fragments ----
  s16x8 fz0 = ldA_g(z + (size_t)arow*64,            ko, 64);
  s16x8 fz1 = ldA_g(z + (size_t)arow*64 + 32,       ko, 32);
  s16x8 fac = ldA_g(action + (size_t)arow*32,       ko, 32);
  s16x8 fc0 = ldA_g(control + (size_t)arow*64,      ko, 64);
  s16x8 fc1 = ldA_g(control + (size_t)arow*64 + 32, ko, 32);
  s16x8 frw = ldA_g(rw + (size_t)arow*16,           ko, 16);

  // ---- tokenizers (X features + dist2) ----
  {
    s16x8 afA[3] = {fac, fz0, fz1};
    token_stage<3,1>(packed, OFF_ACTX, afA, OFF_ACTZ, &fac, act_bx, sX[wid][0], Sc[0], lane);
  }
  {
    s16x8 afC[4] = {fc0, fc1, fz0, fz1};
    s16x8 afCz[2] = {fc0, fc1};
    token_stage<4,2>(packed, OFF_CTLX, afC, OFF_CTLZ, afCz, ctl_bx, sX[wid][1], Sc[1], lane);
  }
  {
    s16x8 afH[3] = {frw, fz0, fz1};
    token_stage<3,1>(packed, OFF_CHTX, afH, OFF_CHTZ, &frw, cht_bx, sX[wid][2], Sc[2], lane);
  }

  // ---- xq = z @ We + be (no tanh) ----
  {
    f32x4 acc[8];
    #pragma unroll
    for (int nt = 0; nt < 8; ++nt) acc[nt] = z4;
    s16x8 afE[2] = {fz0, fz1};
    #pragma unroll
    for (int kt = 0; kt < 2; ++kt)
      #pragma unroll
      for (int nt = 0; nt < 8; ++nt)
        acc[nt] = MF(afE[kt], ldB(packed, OFF_WE + kt*8 + nt, lane), acc[nt]);
    #pragma unroll
    for (int nt = 0; nt < 8; ++nt){
      float bv = be[nt*16 + r15];
      f32x4 v;
      #pragma unroll
      for (int j = 0; j < 4; ++j) v[j] = acc[nt][j] + bv;
      stD(Bu, lane, nt, v);
    }
  }

  // ---- q = xq @ Wq (kept in D-registers) ----
  f32x4 accq[8];
  {
    #pragma unroll
    for (int nt = 0; nt < 8; ++nt) accq[nt] = z4;
    #pragma unroll
    for (int kt = 0; kt < 4; ++kt){
      s16x8 a = ldA_l(Bu, lane, kt);
      #pragma unroll
      for (int nt = 0; nt < 8; ++nt)
        accq[nt] = MF(a, ldB(packed, OFF_WQ + kt*8 + nt, lane), accq[nt]);
    }
  }

  // ---- scores: q . k_t / sqrt(M) - dist2 ----
  #pragma unroll
  for (int t = 0; t < 3; ++t){
    f32x4 acck[8];
    #pragma unroll
    for (int nt = 0; nt < 8; ++nt) acck[nt] = z4;
    #pragma unroll
    for (int kt = 0; kt < 4; ++kt){
      s16x8 a = ldA_l(sX[wid][t], lane, kt);
      #pragma unroll
      for (int nt = 0; nt < 8; ++nt)
        acck[nt] = MF(a, ldB(packed, OFF_WK + kt*8 + nt, lane), acck[nt]);
    }
    float sp[4];
    #pragma unroll
    for (int j = 0; j < 4; ++j){
      float s = 0.f;
      #pragma unroll
      for (int nt = 0; nt < 8; ++nt) s += acck[nt][j]*accq[nt][j];
      sp[j] = s;
    }
    #pragma unroll
    for (int m = 1; m < 16; m <<= 1){
      #pragma unroll
      for (int j = 0; j < 4; ++j) sp[j] += __shfl_xor(sp[j], m);
    }
    if (r15 == 0){
      #pragma unroll
      for (int j = 0; j < 4; ++j) Sc[t][rb+j] += sp[j]*0.0883883476483184f; // 1/sqrt(128)
    }
  }

  // ---- 3-way softmax per row ----
  if (lane < 16){
    float s0 = Sc[0][lane], s1 = Sc[1][lane], s2 = Sc[2][lane];
    float m = fmaxf(s0, fmaxf(s1, s2));
    float e0 = __expf(s0 - m), e1 = __expf(s1 - m), e2 = __expf(s2 - m);
    float inv = 1.f/(e0 + e1 + e2);
    Sc[0][lane] = e0*inv; Sc[1][lane] = e1*inv; Sc[2][lane] = e2*inv;
  }

  // ---- feat_pre = sum_t attn_t * (x_t @ Wv) ----
  f32x4 accf[8];
  #pragma unroll
  for (int nt = 0; nt < 8; ++nt) accf[nt] = z4;
  #pragma unroll
  for (int t = 0; t < 3; ++t){
    f32x4 accv[8];
    #pragma unroll
    for (int nt = 0; nt < 8; ++nt) accv[nt] = z4;
    #pragma unroll
    for (int kt = 0; kt < 4; ++kt){
      s16x8 a = ldA_l(sX[wid][t], lane, kt);
      #pragma unroll
      for (int nt = 0; nt < 8; ++nt)
        accv[nt] = MF(a, ldB(packed, OFF_WV + kt*8 + nt, lane), accv[nt]);
    }
    float at[4];
    #pragma unroll
    for (int j = 0; j < 4; ++j) at[j] = Sc[t][rb+j];
    #pragma unroll
    for (int nt = 0; nt < 8; ++nt)
      #pragma unroll
      for (int j = 0; j < 4; ++j) accf[nt][j] += at[j]*accv[nt][j];
  }
  #pragma unroll
  for (int nt = 0; nt < 8; ++nt) stD(Bu, lane, nt, accf[nt]);

  // ---- feat = feat_pre @ Wo ----
  f32x4 accF[8];
  #pragma unroll
  for (int nt = 0; nt < 8; ++nt) accF[nt] = z4;
  #pragma unroll
  for (int kt = 0; kt < 4; ++kt){
    s16x8 a = ldA_l(Bu, lane, kt);
    #pragma unroll
    for (int nt = 0; nt < 8; ++nt)
      accF[nt] = MF(a, ldB(packed, OFF_WO + kt*8 + nt, lane), accF[nt]);
  }

  // cons head partials (raw cons_W; scaled by inv sigma later)
  float consp[4] = {0.f,0.f,0.f,0.f};
  #pragma unroll
  for (int nt = 0; nt < 8; ++nt){
    float cw = consW[nt*16 + r15];
    #pragma unroll
    for (int j = 0; j < 4; ++j) consp[j] += accF[nt][j]*cw;
  }
  #pragma unroll
  for (int nt = 0; nt < 8; ++nt) stD(Bu, lane, nt, accF[nt]);

  // ---- form head: rf = feat @ form_W (then scale + bias) ----
  f32x4 accR[4];
  #pragma unroll
  for (int nt = 0; nt < 4; ++nt) accR[nt] = z4;
  #pragma unroll
  for (int kt = 0; kt < 4; ++kt){
    s16x8 a = ldA_l(Bu, lane, kt);
    #pragma unroll
    for (int nt = 0; nt < 4; ++nt)
      accR[nt] = MF(a, ldB(packed, OFF_FORM + kt*4 + nt, lane), accR[nt]);
  }

  // ---- epilogue ----
  const float inv_f = sig[0], inv_c = sig[1], cb = consb[0];
  float fb[4];
  #pragma unroll
  for (int nt = 0; nt < 4; ++nt) fb[nt] = formb[nt*16 + r15];
  float tot[4];
  #pragma unroll
  for (int j = 0; j < 4; ++j){
    int grow = g0 + rb + j;
    float s = consp[j]*inv_c;
    #pragma unroll
    for (int nt = 0; nt < 4; ++nt){
      float rf = accR[nt][j]*inv_f + fb[nt];
      s += rf * control[(size_t)grow*64 + nt*16 + r15];
    }
    tot[j] = s;
  }
  #pragma unroll
  for (int m = 1; m < 16; m <<= 1){
    #pragma unroll
    for (int j = 0; j < 4; ++j) tot[j] += __shfl_xor(tot[j], m);
  }
  if (r15 == 0){
    #pragma unroll
    for (int j = 0; j < 4; ++j) out[g0 + rb + j] = tot[j] + cb;
  }
}

extern "C" void kernel_launch(void* const* d_in, const int* in_sizes, int n_in,
                              void* d_out, int out_size, void* d_ws, size_t ws_size,
                              hipStream_t stream)
{
  const float* z      = (const float*)d_in[0];
  const float* action = (const float*)d_in[1];
  const float* rw     = (const float*)d_in[2];
  const float* control= (const float*)d_in[3];
  const float* actWx  = (const float*)d_in[4];
  const float* actbx  = (const float*)d_in[5];
  const float* actWz  = (const float*)d_in[6];
  const float* ctlWx  = (const float*)d_in[7];
  const float* ctlbx  = (const float*)d_in[8];
  const float* ctlWz  = (const float*)d_in[9];
  const float* chtWx  = (const float*)d_in[10];
  const float* chtbx  = (const float*)d_in[11];
  const float* chtWz  = (const float*)d_in[12];
  const float* We     = (const float*)d_in[13];
  const float* be     = (const float*)d_in[14];
  const float* Wq     = (const float*)d_in[15];
  const float* Wk     = (const float*)d_in[16];
  const float* Wv     = (const float*)d_in[17];
  const float* Wo     = (const float*)d_in[18];
  const float* consW  = (const float*)d_in[19];
  const float* consb  = (const float*)d_in[20];
  const float* formW  = (const float*)d_in[21];
  const float* formb  = (const float*)d_in[22];
  float* out = (float*)d_out;

  unsigned short* packed = (unsigned short*)d_ws;
  float* sig = (float*)((char*)d_ws + SIG_OFF);

  hipLaunchKernelGGL(pack_k, dim3(N_TILES), dim3(512), 0, stream,
                     actWx, ctlWx, chtWx, actWz, ctlWz, chtWz,
                     We, Wq, Wk, Wv, Wo, formW, packed);
  hipLaunchKernelGGL(sigma_k, dim3(1), dim3(256), 0, stream, formW, consW, sig);
  hipLaunchKernelGGL(reward_main, dim3(32768/64), dim3(256), 0, stream,
                     z, action, rw, control, actbx, ctlbx, chtbx, be,
                     consW, consb, formb, packed, sig, out);
}

// Round 2
// 107.160 us; speedup vs baseline: 1.2925x; 1.2925x over previous
//
#include <hip/hip_runtime.h>
#include <hip/hip_bf16.h>

// RewardHead fused kernel for MI355X (gfx950).
// B=32768 rows, D=64, A=32, K=16, M=128. Output: [B,1] f32.
//
// d_ws layout: [0, 256KB): packed bf16 MFMA B-fragments for all weights
//              [256KB, +8): {1/(sigma_form+1e-6), 1/(sigma_cons+1e-6)}

typedef float f32x4 __attribute__((ext_vector_type(4)));
typedef short s16x8 __attribute__((ext_vector_type(8)));

#define OFF_ACTX 0
#define OFF_CTLX 24
#define OFF_CHTX 56
#define OFF_ACTZ 80
#define OFF_CTLZ 84
#define OFF_CHTZ 92
#define OFF_WE   96
#define OFF_WQ   112
#define OFF_WK   144
#define OFF_WV   176
#define OFF_WO   208
#define OFF_FORM 240
#define N_TILES  256
#define SIG_OFF  (N_TILES*1024)   // bytes into d_ws

__device__ __forceinline__ unsigned short f2bf(float f){
  unsigned u = __float_as_uint(f);
  u += 0x7fffu + ((u>>16)&1u);          // RNE
  return (unsigned short)(u>>16);
}

union V8 { s16x8 v; unsigned short us[8]; uint4 q; };

__device__ __forceinline__ f32x4 MF(s16x8 a, s16x8 b, f32x4 c){
  return __builtin_amdgcn_mfma_f32_16x16x32_bf16(a, b, c, 0, 0, 0);
}

// B-fragment: one 16B load per lane from pre-packed tiles.
__device__ __forceinline__ s16x8 ldB(const unsigned short* __restrict__ pk, int tile, int lane){
  V8 t;
  t.q = *reinterpret_cast<const uint4*>(pk + (((size_t)tile<<6) + lane)*8);
  return t.v;
}

// A-fragment from global f32 row data: 8 consecutive dims starting at ko,
// zero-filled when ko >= limit (K padding).
__device__ __forceinline__ s16x8 ldA_g(const float* __restrict__ p, int ko, int limit){
  V8 t;
  if (ko < limit){
    const float4* q4 = reinterpret_cast<const float4*>(p + ko);
    float4 a = q4[0], b = q4[1];
    t.us[0]=f2bf(a.x); t.us[1]=f2bf(a.y); t.us[2]=f2bf(a.z); t.us[3]=f2bf(a.w);
    t.us[4]=f2bf(b.x); t.us[5]=f2bf(b.y); t.us[6]=f2bf(b.z); t.us[7]=f2bf(b.w);
  } else {
    t.q = make_uint4(0u,0u,0u,0u);
  }
  return t.v;
}

// A-fragment from a 16x128 bf16 LDS tile with XOR swizzle (byte ^= (row&7)<<4).
__device__ __forceinline__ s16x8 ldA_l(const unsigned short* buf, int lane, int kt){
  int row = lane & 15;
  int bo = (row<<8) + (kt<<6) + ((lane>>4)<<4);
  bo ^= (row & 7) << 4;
  return *reinterpret_cast<const s16x8*>(buf + (bo>>1));
}

// Store one D-tile column-slice (4 rows) to swizzled LDS as bf16.
__device__ __forceinline__ void stD(unsigned short* buf, int lane, int nt, f32x4 v){
  int colb = (((nt<<4) + (lane&15))<<1);
  int rb = (lane>>4)<<2;
  #pragma unroll
  for (int j=0;j<4;++j){
    int row = rb + j;
    int bo = ((row<<8) + colb) ^ ((row&7)<<4);
    buf[bo>>1] = f2bf(v[j]);
  }
}

__device__ __forceinline__ float tanh_fast(float x){
  x = fminf(15.f, fmaxf(-15.f, x));
  float e = __expf(2.f*x);
  return 1.f - __fdividef(2.f, e + 1.f);
}

// ---------------- weight pre-pack ----------------
__global__ __launch_bounds__(512) void pack_k(
    const float* __restrict__ aWx, const float* __restrict__ cWx, const float* __restrict__ hWx,
    const float* __restrict__ aWz, const float* __restrict__ cWz, const float* __restrict__ hWz,
    const float* __restrict__ We,  const float* __restrict__ Wq,  const float* __restrict__ Wk,
    const float* __restrict__ Wv,  const float* __restrict__ Wo,  const float* __restrict__ fW,
    unsigned short* __restrict__ packed)
{
  int tile = blockIdx.x;
  const float* W; int N; int kind = 0; int base;
  if      (tile < 24) { W=aWx; N=128; base=OFF_ACTX; }
  else if (tile < 56) { W=cWx; N=128; base=OFF_CTLX; }
  else if (tile < 80) { W=hWx; N=128; base=OFF_CHTX; kind=1; }  // rows: 0-15 rw, pad 16-31, 32-95 -> z rows 16-79
  else if (tile < 84) { W=aWz; N=64;  base=OFF_ACTZ; }
  else if (tile < 92) { W=cWz; N=64;  base=OFF_CTLZ; }
  else if (tile < 96) { W=hWz; N=64;  base=OFF_CHTZ; kind=2; }  // rows 0-15 real, 16-31 pad
  else if (tile < 112){ W=We;  N=128; base=OFF_WE; }
  else if (tile < 144){ W=Wq;  N=128; base=OFF_WQ; }
  else if (tile < 176){ W=Wk;  N=128; base=OFF_WK; }
  else if (tile < 208){ W=Wv;  N=128; base=OFF_WV; }
  else if (tile < 240){ W=Wo;  N=128; base=OFF_WO; }
  else                { W=fW;  N=64;  base=OFF_FORM; }
  int NT = N >> 4;
  int lt = tile - base;
  int nt = lt % NT, kt = lt / NT;
  int tid = threadIdx.x;
  int lane = tid >> 3, i = tid & 7;
  int k = kt*32 + ((lane>>4)<<3) + i;
  int n = nt*16 + (lane & 15);
  int sr = k;
  if (kind == 1) sr = (k < 16) ? k : (k < 32 ? -1 : k - 16);
  else if (kind == 2) sr = (k < 16) ? k : -1;
  float v = (sr >= 0) ? W[(size_t)sr*N + n] : 0.f;
  packed[(((size_t)tile<<6) + lane)*8 + i] = f2bf(v);
}

// ---------------- spectral norms (parallel squaring chain) ----------------
// sigma(form_W):  G = W^T W (64x64).  6 Frobenius-normalized squarings give
// G^64; sigma = exp(L/128) with L the accumulated log-scale (lambda_max bias
// C^(1/128) <= +0.4%, safe direction).  16 waves, no serial power iteration.
__global__ __launch_bounds__(1024) void sigma_k(
    const float* __restrict__ formW, const float* __restrict__ consW,
    float* __restrict__ sig)
{
  __shared__ float Wt[64][132];   // Wt[c][m] = W[m][c]
  __shared__ float R[64][68];
  __shared__ float red[16];
  __shared__ float cons_s;
  const int tid = threadIdx.x;
  const int w = tid >> 6, l = tid & 63;
  const int i0 = w << 2;

  for (int idx = tid; idx < 8192; idx += 1024)
    Wt[idx & 63][idx >> 6] = formW[idx];

  if (w == 15){
    float c0 = consW[l], c1 = consW[l + 64];
    float s = c0*c0 + c1*c1;
    #pragma unroll
    for (int m = 1; m < 64; m <<= 1) s += __shfl_xor(s, m);
    if (l == 0) cons_s = s;
  }
  __syncthreads();

  // G = Wt rows dotted: wave w computes rows i0..i0+3, lane l = column.
  {
    float a0=0.f,a1=0.f,a2=0.f,a3=0.f;
    #pragma unroll 4
    for (int m4 = 0; m4 < 128; m4 += 4){
      float4 xc = *(const float4*)&Wt[l][m4];
      float4 b0 = *(const float4*)&Wt[i0+0][m4];
      float4 b1 = *(const float4*)&Wt[i0+1][m4];
      float4 b2 = *(const float4*)&Wt[i0+2][m4];
      float4 b3 = *(const float4*)&Wt[i0+3][m4];
      a0 += b0.x*xc.x + b0.y*xc.y + b0.z*xc.z + b0.w*xc.w;
      a1 += b1.x*xc.x + b1.y*xc.y + b1.z*xc.z + b1.w*xc.w;
      a2 += b2.x*xc.x + b2.y*xc.y + b2.z*xc.z + b2.w*xc.w;
      a3 += b3.x*xc.x + b3.y*xc.y + b3.z*xc.z + b3.w*xc.w;
    }
    R[i0+0][l]=a0; R[i0+1][l]=a1; R[i0+2][l]=a2; R[i0+3][l]=a3;
  }
  __syncthreads();

  float L = 0.f;
  for (int it = 0; it < 6; ++it){
    float a0=0.f,a1=0.f,a2=0.f,a3=0.f;
    #pragma unroll 4
    for (int m4 = 0; m4 < 64; m4 += 4){
      float4 xc = *(const float4*)&R[l][m4];   // row l (== column l, symmetric)
      float4 b0 = *(const float4*)&R[i0+0][m4];
      float4 b1 = *(const float4*)&R[i0+1][m4];
      float4 b2 = *(const float4*)&R[i0+2][m4];
      float4 b3 = *(const float4*)&R[i0+3][m4];
      a0 += b0.x*xc.x + b0.y*xc.y + b0.z*xc.z + b0.w*xc.w;
      a1 += b1.x*xc.x + b1.y*xc.y + b1.z*xc.z + b1.w*xc.w;
      a2 += b2.x*xc.x + b2.y*xc.y + b2.z*xc.z + b2.w*xc.w;
      a3 += b3.x*xc.x + b3.y*xc.y + b3.z*xc.z + b3.w*xc.w;
    }
    float nr = a0*a0+a1*a1+a2*a2+a3*a3;
    #pragma unroll
    for (int m = 1; m < 64; m <<= 1) nr += __shfl_xor(nr, m);
    if (l == 0) red[w] = nr;
    __syncthreads();                 // reads of R done; red visible
    float tot = 0.f;
    #pragma unroll
    for (int k = 0; k < 16; ++k) tot += red[k];
    float s = sqrtf(tot);
    L = 2.f*L + logf(s);
    float inv = 1.f/s;
    R[i0+0][l]=a0*inv; R[i0+1][l]=a1*inv; R[i0+2][l]=a2*inv; R[i0+3][l]=a3*inv;
    __syncthreads();                 // writes visible for next iter
  }
  if (tid == 0){
    float sf = expf(L*(1.f/128.f));  // sigma_max estimate
    sig[0] = 1.f/(sf + 1e-6f);
    sig[1] = 1.f/(sqrtf(cons_s) + 1e-6f);
  }
}

// ---------------- tokenizer stage (per wave) ----------------
template<int KTX, int KTZ>
__device__ __forceinline__ void token_stage(
    const unsigned short* __restrict__ pk, int offX, const s16x8* afX,
    int offZ, const s16x8* afZ, const float* __restrict__ bx,
    unsigned short* Xdst, float* ScT, int lane)
{
  const int r15 = lane & 15, rb = (lane>>4)<<2;
  const f32x4 z4 = {0.f,0.f,0.f,0.f};
  f32x4 acc[8];
  #pragma unroll
  for (int nt = 0; nt < 8; ++nt) acc[nt] = z4;
  #pragma unroll
  for (int kt = 0; kt < KTX; ++kt){
    #pragma unroll
    for (int nt = 0; nt < 8; ++nt)
      acc[nt] = MF(afX[kt], ldB(pk, offX + kt*8 + nt, lane), acc[nt]);
  }
  #pragma unroll
  for (int nt = 0; nt < 8; ++nt){
    float bv = bx[nt*16 + r15];
    f32x4 v;
    #pragma unroll
    for (int j = 0; j < 4; ++j) v[j] = tanh_fast(acc[nt][j] + bv);
    stD(Xdst, lane, nt, v);
  }
  // dist2 = || tanh(u @ Wz) ||^2
  f32x4 a2[4];
  #pragma unroll
  for (int nt = 0; nt < 4; ++nt) a2[nt] = z4;
  #pragma unroll
  for (int kt = 0; kt < KTZ; ++kt){
    #pragma unroll
    for (int nt = 0; nt < 4; ++nt)
      a2[nt] = MF(afZ[kt], ldB(pk, offZ + kt*4 + nt, lane), a2[nt]);
  }
  float d2[4];
  #pragma unroll
  for (int j = 0; j < 4; ++j){
    float s = 0.f;
    #pragma unroll
    for (int nt = 0; nt < 4; ++nt){ float t = tanh_fast(a2[nt][j]); s += t*t; }
    d2[j] = s;
  }
  #pragma unroll
  for (int m = 1; m < 16; m <<= 1){
    #pragma unroll
    for (int j = 0; j < 4; ++j) d2[j] += __shfl_xor(d2[j], m);
  }
  if (r15 == 0){
    #pragma unroll
    for (int j = 0; j < 4; ++j) ScT[rb+j] = -d2[j];
  }
}

// ---------------- main fused kernel ----------------
// 4 waves/block, each wave owns 16 rows.  __syncthreads() between weight
// phases aligns the waves so the block's packed-tile reads hit L1.
__global__ __launch_bounds__(256) void reward_main(
    const float* __restrict__ z, const float* __restrict__ action,
    const float* __restrict__ rw, const float* __restrict__ control,
    const float* __restrict__ act_bx, const float* __restrict__ ctl_bx,
    const float* __restrict__ cht_bx, const float* __restrict__ be,
    const float* __restrict__ consW, const float* __restrict__ consb,
    const float* __restrict__ formb,
    const unsigned short* __restrict__ packed, const float* __restrict__ sig,
    float* __restrict__ out)
{
  __shared__ unsigned short sX[4][3][2048];
  __shared__ unsigned short sBuf[4][2048];
  __shared__ float sSc[4][3][16];

  const int wid  = threadIdx.x >> 6;
  const int lane = threadIdx.x & 63;
  const int g0   = blockIdx.x*64 + wid*16;
  const int r15  = lane & 15;
  const int hi   = lane >> 4;
  const int ko   = hi << 3;
  const int rb   = hi << 2;
  const int arow = g0 + r15;

  unsigned short* Bu = sBuf[wid];
  float (*Sc)[16] = sSc[wid];
  const f32x4 z4 = {0.f,0.f,0.f,0.f};

  // ---- raw-input A-fragments ----
  s16x8 fz0 = ldA_g(z + (size_t)arow*64,            ko, 64);
  s16x8 fz1 = ldA_g(z + (size_t)arow*64 + 32,       ko, 32);
  s16x8 fac = ldA_g(action + (size_t)arow*32,       ko, 32);
  s16x8 fc0 = ldA_g(control + (size_t)arow*64,      ko, 64);
  s16x8 fc1 = ldA_g(control + (size_t)arow*64 + 32, ko, 32);
  s16x8 frw = ldA_g(rw + (size_t)arow*16,           ko, 16);

  // ---- tokenizers ----
  {
    s16x8 afA[3] = {fac, fz0, fz1};
    token_stage<3,1>(packed, OFF_ACTX, afA, OFF_ACTZ, &fac, act_bx, sX[wid][0], Sc[0], lane);
  }
  __syncthreads();
  {
    s16x8 afC[4] = {fc0, fc1, fz0, fz1};
    s16x8 afCz[2] = {fc0, fc1};
    token_stage<4,2>(packed, OFF_CTLX, afC, OFF_CTLZ, afCz, ctl_bx, sX[wid][1], Sc[1], lane);
  }
  __syncthreads();
  {
    s16x8 afH[3] = {frw, fz0, fz1};
    token_stage<3,1>(packed, OFF_CHTX, afH, OFF_CHTZ, &frw, cht_bx, sX[wid][2], Sc[2], lane);
  }
  __syncthreads();

  // ---- xq = z @ We + be ----
  {
    f32x4 acc[8];
    #pragma unroll
    for (int nt = 0; nt < 8; ++nt) acc[nt] = z4;
    s16x8 afE[2] = {fz0, fz1};
    #pragma unroll
    for (int kt = 0; kt < 2; ++kt)
      #pragma unroll
      for (int nt = 0; nt < 8; ++nt)
        acc[nt] = MF(afE[kt], ldB(packed, OFF_WE + kt*8 + nt, lane), acc[nt]);
    #pragma unroll
    for (int nt = 0; nt < 8; ++nt){
      float bv = be[nt*16 + r15];
      f32x4 v;
      #pragma unroll
      for (int j = 0; j < 4; ++j) v[j] = acc[nt][j] + bv;
      stD(Bu, lane, nt, v);
    }
  }
  __syncthreads();

  // ---- q = xq @ Wq (D-registers) ----
  f32x4 accq[8];
  {
    #pragma unroll
    for (int nt = 0; nt < 8; ++nt) accq[nt] = z4;
    #pragma unroll
    for (int kt = 0; kt < 4; ++kt){
      s16x8 a = ldA_l(Bu, lane, kt);
      #pragma unroll
      for (int nt = 0; nt < 8; ++nt)
        accq[nt] = MF(a, ldB(packed, OFF_WQ + kt*8 + nt, lane), accq[nt]);
    }
  }
  __syncthreads();

  // ---- scores: each Wk B-load shared across all 3 tokens; per-kt MFMA
  // partials (C=0) dotted immediately with q (linearity of the dot). ----
  float sp[3][4];
  #pragma unroll
  for (int t = 0; t < 3; ++t)
    #pragma unroll
    for (int j = 0; j < 4; ++j) sp[t][j] = 0.f;
  #pragma unroll
  for (int kt = 0; kt < 4; ++kt){
    s16x8 a0 = ldA_l(sX[wid][0], lane, kt);
    s16x8 a1 = ldA_l(sX[wid][1], lane, kt);
    s16x8 a2 = ldA_l(sX[wid][2], lane, kt);
    #pragma unroll
    for (int nt = 0; nt < 8; ++nt){
      s16x8 b = ldB(packed, OFF_WK + kt*8 + nt, lane);
      f32x4 d0 = MF(a0, b, z4);
      f32x4 d1 = MF(a1, b, z4);
      f32x4 d2 = MF(a2, b, z4);
      #pragma unroll
      for (int j = 0; j < 4; ++j){
        sp[0][j] += d0[j]*accq[nt][j];
        sp[1][j] += d1[j]*accq[nt][j];
        sp[2][j] += d2[j]*accq[nt][j];
      }
    }
  }
  #pragma unroll
  for (int m = 1; m < 16; m <<= 1)
    #pragma unroll
    for (int t = 0; t < 3; ++t)
      #pragma unroll
      for (int j = 0; j < 4; ++j) sp[t][j] += __shfl_xor(sp[t][j], m);
  if (r15 == 0){
    #pragma unroll
    for (int t = 0; t < 3; ++t)
      #pragma unroll
      for (int j = 0; j < 4; ++j) Sc[t][rb+j] += sp[t][j]*0.0883883476483184f;
  }

  // ---- 3-way softmax per row ----
  if (lane < 16){
    float s0 = Sc[0][lane], s1 = Sc[1][lane], s2 = Sc[2][lane];
    float m = fmaxf(s0, fmaxf(s1, s2));
    float e0 = __expf(s0 - m), e1 = __expf(s1 - m), e2 = __expf(s2 - m);
    float inv = 1.f/(e0 + e1 + e2);
    Sc[0][lane] = e0*inv; Sc[1][lane] = e1*inv; Sc[2][lane] = e2*inv;
  }
  __syncthreads();

  // ---- feat_pre: Wv B-loads shared across tokens, attn applied per kt ----
  float at[3][4];
  #pragma unroll
  for (int t = 0; t < 3; ++t)
    #pragma unroll
    for (int j = 0; j < 4; ++j) at[t][j] = Sc[t][rb+j];
  f32x4 accf[8];
  #pragma unroll
  for (int nt = 0; nt < 8; ++nt) accf[nt] = z4;
  #pragma unroll
  for (int kt = 0; kt < 4; ++kt){
    s16x8 a0 = ldA_l(sX[wid][0], lane, kt);
    s16x8 a1 = ldA_l(sX[wid][1], lane, kt);
    s16x8 a2 = ldA_l(sX[wid][2], lane, kt);
    #pragma unroll
    for (int nt = 0; nt < 8; ++nt){
      s16x8 b = ldB(packed, OFF_WV + kt*8 + nt, lane);
      f32x4 d0 = MF(a0, b, z4);
      f32x4 d1 = MF(a1, b, z4);
      f32x4 d2 = MF(a2, b, z4);
      #pragma unroll
      for (int j = 0; j < 4; ++j)
        accf[nt][j] += at[0][j]*d0[j] + at[1][j]*d1[j] + at[2][j]*d2[j];
    }
  }
  #pragma unroll
  for (int nt = 0; nt < 8; ++nt) stD(Bu, lane, nt, accf[nt]);
  __syncthreads();

  // ---- feat = feat_pre @ Wo ----
  f32x4 accF[8];
  #pragma unroll
  for (int nt = 0; nt < 8; ++nt) accF[nt] = z4;
  #pragma unroll
  for (int kt = 0; kt < 4; ++kt){
    s16x8 a = ldA_l(Bu, lane, kt);
    #pragma unroll
    for (int nt = 0; nt < 8; ++nt)
      accF[nt] = MF(a, ldB(packed, OFF_WO + kt*8 + nt, lane), accF[nt]);
  }

  float consp[4] = {0.f,0.f,0.f,0.f};
  #pragma unroll
  for (int nt = 0; nt < 8; ++nt){
    float cw = consW[nt*16 + r15];
    #pragma unroll
    for (int j = 0; j < 4; ++j) consp[j] += accF[nt][j]*cw;
  }
  #pragma unroll
  for (int nt = 0; nt < 8; ++nt) stD(Bu, lane, nt, accF[nt]);

  // ---- form head ----
  f32x4 accR[4];
  #pragma unroll
  for (int nt = 0; nt < 4; ++nt) accR[nt] = z4;
  #pragma unroll
  for (int kt = 0; kt < 4; ++kt){
    s16x8 a = ldA_l(Bu, lane, kt);
    #pragma unroll
    for (int nt = 0; nt < 4; ++nt)
      accR[nt] = MF(a, ldB(packed, OFF_FORM + kt*4 + nt, lane), accR[nt]);
  }

  // ---- epilogue ----
  const float inv_f = sig[0], inv_c = sig[1], cb = consb[0];
  float fb[4];
  #pragma unroll
  for (int nt = 0; nt < 4; ++nt) fb[nt] = formb[nt*16 + r15];
  float tot[4];
  #pragma unroll
  for (int j = 0; j < 4; ++j){
    int grow = g0 + rb + j;
    float s = consp[j]*inv_c;
    #pragma unroll
    for (int nt = 0; nt < 4; ++nt){
      float rf = accR[nt][j]*inv_f + fb[nt];
      s += rf * control[(size_t)grow*64 + nt*16 + r15];
    }
    tot[j] = s;
  }
  #pragma unroll
  for (int m = 1; m < 16; m <<= 1){
    #pragma unroll
    for (int j = 0; j < 4; ++j) tot[j] += __shfl_xor(tot[j], m);
  }
  if (r15 == 0){
    #pragma unroll
    for (int j = 0; j < 4; ++j) out[g0 + rb + j] = tot[j] + cb;
  }
}

extern "C" void kernel_launch(void* const* d_in, const int* in_sizes, int n_in,
                              void* d_out, int out_size, void* d_ws, size_t ws_size,
                              hipStream_t stream)
{
  const float* z      = (const float*)d_in[0];
  const float* action = (const float*)d_in[1];
  const float* rw     = (const float*)d_in[2];
  const float* control= (const float*)d_in[3];
  const float* actWx  = (const float*)d_in[4];
  const float* actbx  = (const float*)d_in[5];
  const float* actWz  = (const float*)d_in[6];
  const float* ctlWx  = (const float*)d_in[7];
  const float* ctlbx  = (const float*)d_in[8];
  const float* ctlWz  = (const float*)d_in[9];
  const float* chtWx  = (const float*)d_in[10];
  const float* chtbx  = (const float*)d_in[11];
  const float* chtWz  = (const float*)d_in[12];
  const float* We     = (const float*)d_in[13];
  const float* be     = (const float*)d_in[14];
  const float* Wq     = (const float*)d_in[15];
  const float* Wk     = (const float*)d_in[16];
  const float* Wv     = (const float*)d_in[17];
  const float* Wo     = (const float*)d_in[18];
  const float* consW  = (const float*)d_in[19];
  const float* consb  = (const float*)d_in[20];
  const float* formW  = (const float*)d_in[21];
  const float* formb  = (const float*)d_in[22];
  float* out = (float*)d_out;

  unsigned short* packed = (unsigned short*)d_ws;
  float* sig = (float*)((char*)d_ws + SIG_OFF);

  hipLaunchKernelGGL(pack_k, dim3(N_TILES), dim3(512), 0, stream,
                     actWx, ctlWx, chtWx, actWz, ctlWz, chtWz,
                     We, Wq, Wk, Wv, Wo, formW, packed);
  hipLaunchKernelGGL(sigma_k, dim3(1), dim3(1024), 0, stream, formW, consW, sig);
  hipLaunchKernelGGL(reward_main, dim3(32768/64), dim3(256), 0, stream,
                     z, action, rw, control, actbx, ctlbx, chtbx, be,
                     consW, consb, formb, packed, sig, out);
}

// Round 3
// 66.177 us; speedup vs baseline: 2.0930x; 1.6193x over previous
//
#include <hip/hip_runtime.h>
#include <hip/hip_bf16.h>

// RewardHead fused kernel for MI355X (gfx950) — round 3: folded linear algebra.
// B=32768, D=64, A=32, K=16, M=128. Output: [B,1] f32.
//
// Folds (computed in prep kernel, f32):
//   Weqk  = We @ Wq @ Wk^T            [64,128]   (scores: qW = z@Weqk + bqk)
//   bqk   = be @ Wq @ Wk^T            [128]
//   WvofT = (Wv @ Wo @ form_W)^T      [64,128]   (g = control @ WvofT)
//   wvoc  = Wv @ Wo @ cons_W          [128]
// Then per 16-row tile: 3 tokenizers + qW + g = 128 MFMA, 128 B-tile loads,
// everything else in D-layout registers. No LDS, no barriers in main kernel.
//
// d_ws: [0,128KB) packed bf16 B-fragments (128 tiles x 1KB)
//       [128KB, +8) sig: {1/(sigma_form+eps), 1/(sigma_cons+eps)}
//       [128KB+256, ...) prep f32: Weqk[8192], WvofT[8192], bqk[128](@16384), wvoc[128](@16512)

typedef float f32x4 __attribute__((ext_vector_type(4)));
typedef short s16x8 __attribute__((ext_vector_type(8)));

#define OFF_ACTX  0
#define OFF_CTLX  24
#define OFF_CHTX  56
#define OFF_ACTZ  80
#define OFF_CTLZ  84
#define OFF_CHTZ  92
#define OFF_WEQK  96
#define OFF_WVOFT 112
#define N_TILES   128
#define SIG_OFF   (N_TILES*1024)
#define PREP_OFF  (SIG_OFF + 256)

__device__ __forceinline__ unsigned short f2bf(float f){
  unsigned u = __float_as_uint(f);
  u += 0x7fffu + ((u>>16)&1u);          // RNE
  return (unsigned short)(u>>16);
}
__device__ __forceinline__ float ubf_lo(unsigned u){ return __uint_as_float(u<<16); }
__device__ __forceinline__ float ubf_hi(unsigned u){ return __uint_as_float(u & 0xffff0000u); }

union V8 { s16x8 v; unsigned short us[8]; uint4 q; };

__device__ __forceinline__ f32x4 MF(s16x8 a, s16x8 b, f32x4 c){
  return __builtin_amdgcn_mfma_f32_16x16x32_bf16(a, b, c, 0, 0, 0);
}

__device__ __forceinline__ s16x8 ldB(const unsigned short* __restrict__ pk, int tile, int lane){
  V8 t;
  t.q = *reinterpret_cast<const uint4*>(pk + (((size_t)tile<<6) + lane)*8);
  return t.v;
}

// A-fragment from global f32 row data (zero-fill when ko >= limit).
__device__ __forceinline__ s16x8 ldA_g(const float* __restrict__ p, int ko, int limit){
  V8 t;
  if (ko < limit){
    const float4* q4 = reinterpret_cast<const float4*>(p + ko);
    float4 a = q4[0], b = q4[1];
    t.us[0]=f2bf(a.x); t.us[1]=f2bf(a.y); t.us[2]=f2bf(a.z); t.us[3]=f2bf(a.w);
    t.us[4]=f2bf(b.x); t.us[5]=f2bf(b.y); t.us[6]=f2bf(b.z); t.us[7]=f2bf(b.w);
  } else {
    t.q = make_uint4(0u,0u,0u,0u);
  }
  return t.v;
}

__device__ __forceinline__ float tanh_fast(float x){
  x = fminf(15.f, fmaxf(-15.f, x));
  float e = __expf(2.f*x);
  return 1.f - __fdividef(2.f, e + 1.f);
}

// ---------------- prep (folded matrices) + sigma ----------------
// blocks 0..63: Weqk row d; block 64: bqk; blocks 65..128: WvofT row d;
// block 129: wvoc; block 130: spectral norms (round-2 algorithm).
__global__ __launch_bounds__(1024) void prep_sigma_k(
    const float* __restrict__ We, const float* __restrict__ be,
    const float* __restrict__ Wq, const float* __restrict__ Wk,
    const float* __restrict__ Wv, const float* __restrict__ Wo,
    const float* __restrict__ consW, const float* __restrict__ formW,
    float* __restrict__ prep, float* __restrict__ sig)
{
  __shared__ float tsh[128];
  __shared__ float Wt[64][132];
  __shared__ float R[64][68];
  __shared__ float red[16];
  __shared__ float cons_s;
  const int b = blockIdx.x;
  const int tid = threadIdx.x;

  if (b < 130){
    if (b <= 64){
      // t = row @ Wq ; out[n] = sum_p t[p] * Wk[n,p]
      const float* rowv = (b == 64) ? be : (We + (size_t)b*128);
      if (tid < 128){
        float s = 0.f;
        for (int m = 0; m < 128; ++m) s += rowv[m]*Wq[(size_t)m*128 + tid];
        tsh[tid] = s;
      }
      __syncthreads();
      if (tid < 128){
        float s = 0.f;
        for (int p = 0; p < 128; ++p) s += tsh[p]*Wk[(size_t)tid*128 + p];
        if (b == 64) prep[16384 + tid] = s;
        else         prep[(size_t)b*128 + tid] = s;
      }
    } else {
      int d = b - 65;                        // 0..63 WvofT row d; 64 -> wvoc
      if (tid < 128){
        float s = 0.f;
        if (d < 64){ for (int j = 0; j < 128; ++j) s += Wo[(size_t)tid*128 + j]*formW[(size_t)j*64 + d]; }
        else       { for (int j = 0; j < 128; ++j) s += Wo[(size_t)tid*128 + j]*consW[j]; }
        tsh[tid] = s;
      }
      __syncthreads();
      if (tid < 128){
        float s = 0.f;
        for (int p = 0; p < 128; ++p) s += Wv[(size_t)tid*128 + p]*tsh[p];
        if (d < 64) prep[8192 + (size_t)d*128 + tid] = s;
        else        prep[16512 + tid] = s;
      }
    }
    return;
  }

  // ---- block 130: spectral norms (G = W^T W, 6 normalized squarings) ----
  const int w = tid >> 6, l = tid & 63;
  const int i0 = w << 2;

  for (int idx = tid; idx < 8192; idx += 1024)
    Wt[idx & 63][idx >> 6] = formW[idx];

  if (w == 15){
    float c0 = consW[l], c1 = consW[l + 64];
    float s = c0*c0 + c1*c1;
    #pragma unroll
    for (int m = 1; m < 64; m <<= 1) s += __shfl_xor(s, m);
    if (l == 0) cons_s = s;
  }
  __syncthreads();

  {
    float a0=0.f,a1=0.f,a2=0.f,a3=0.f;
    #pragma unroll 4
    for (int m4 = 0; m4 < 128; m4 += 4){
      float4 xc = *(const float4*)&Wt[l][m4];
      float4 b0 = *(const float4*)&Wt[i0+0][m4];
      float4 b1 = *(const float4*)&Wt[i0+1][m4];
      float4 b2 = *(const float4*)&Wt[i0+2][m4];
      float4 b3 = *(const float4*)&Wt[i0+3][m4];
      a0 += b0.x*xc.x + b0.y*xc.y + b0.z*xc.z + b0.w*xc.w;
      a1 += b1.x*xc.x + b1.y*xc.y + b1.z*xc.z + b1.w*xc.w;
      a2 += b2.x*xc.x + b2.y*xc.y + b2.z*xc.z + b2.w*xc.w;
      a3 += b3.x*xc.x + b3.y*xc.y + b3.z*xc.z + b3.w*xc.w;
    }
    R[i0+0][l]=a0; R[i0+1][l]=a1; R[i0+2][l]=a2; R[i0+3][l]=a3;
  }
  __syncthreads();

  float L = 0.f;
  for (int it = 0; it < 6; ++it){
    float a0=0.f,a1=0.f,a2=0.f,a3=0.f;
    #pragma unroll 4
    for (int m4 = 0; m4 < 64; m4 += 4){
      float4 xc = *(const float4*)&R[l][m4];
      float4 b0 = *(const float4*)&R[i0+0][m4];
      float4 b1 = *(const float4*)&R[i0+1][m4];
      float4 b2 = *(const float4*)&R[i0+2][m4];
      float4 b3 = *(const float4*)&R[i0+3][m4];
      a0 += b0.x*xc.x + b0.y*xc.y + b0.z*xc.z + b0.w*xc.w;
      a1 += b1.x*xc.x + b1.y*xc.y + b1.z*xc.z + b1.w*xc.w;
      a2 += b2.x*xc.x + b2.y*xc.y + b2.z*xc.z + b2.w*xc.w;
      a3 += b3.x*xc.x + b3.y*xc.y + b3.z*xc.z + b3.w*xc.w;
    }
    float nr = a0*a0+a1*a1+a2*a2+a3*a3;
    #pragma unroll
    for (int m = 1; m < 64; m <<= 1) nr += __shfl_xor(nr, m);
    if (l == 0) red[w] = nr;
    __syncthreads();
    float tot = 0.f;
    #pragma unroll
    for (int k = 0; k < 16; ++k) tot += red[k];
    float s = sqrtf(tot);
    L = 2.f*L + logf(s);
    float inv = 1.f/s;
    R[i0+0][l]=a0*inv; R[i0+1][l]=a1*inv; R[i0+2][l]=a2*inv; R[i0+3][l]=a3*inv;
    __syncthreads();
  }
  if (tid == 0){
    float sf = expf(L*(1.f/128.f));
    sig[0] = 1.f/(sf + 1e-6f);
    sig[1] = 1.f/(sqrtf(cons_s) + 1e-6f);
  }
}

// ---------------- weight pre-pack (128 tiles) ----------------
__global__ __launch_bounds__(512) void pack_k2(
    const float* __restrict__ aWx, const float* __restrict__ cWx, const float* __restrict__ hWx,
    const float* __restrict__ aWz, const float* __restrict__ cWz, const float* __restrict__ hWz,
    const float* __restrict__ prep, unsigned short* __restrict__ packed)
{
  int tile = blockIdx.x;
  const float* W; int N; int kind = 0; int base;
  if      (tile < 24) { W=aWx;        N=128; base=OFF_ACTX; }
  else if (tile < 56) { W=cWx;        N=128; base=OFF_CTLX; }
  else if (tile < 80) { W=hWx;        N=128; base=OFF_CHTX; kind=1; }
  else if (tile < 84) { W=aWz;        N=64;  base=OFF_ACTZ; }
  else if (tile < 92) { W=cWz;        N=64;  base=OFF_CTLZ; }
  else if (tile < 96) { W=hWz;        N=64;  base=OFF_CHTZ; kind=2; }
  else if (tile < 112){ W=prep;       N=128; base=OFF_WEQK; }
  else                { W=prep+8192;  N=128; base=OFF_WVOFT; }
  int NT = N >> 4;
  int lt = tile - base;
  int nt = lt % NT, kt = lt / NT;
  int tid = threadIdx.x;
  int lane = tid >> 3, i = tid & 7;
  int k = kt*32 + ((lane>>4)<<3) + i;
  int n = nt*16 + (lane & 15);
  int sr = k;
  if (kind == 1) sr = (k < 16) ? k : (k < 32 ? -1 : k - 16);
  else if (kind == 2) sr = (k < 16) ? k : -1;
  float v = (sr >= 0) ? W[(size_t)sr*N + n] : 0.f;
  packed[(((size_t)tile<<6) + lane)*8 + i] = f2bf(v);
}

// ---------------- tokenizer (pure registers) ----------------
template<int KTX, int KTZ>
__device__ __forceinline__ void token_reg(
    const unsigned short* __restrict__ pk, int offX, const s16x8* afX,
    int offZ, const s16x8* afZ, const float* __restrict__ bx,
    int lane, unsigned xp[8][2], float d2o[4])
{
  const int r15 = lane & 15;
  const f32x4 z4 = {0.f,0.f,0.f,0.f};
  f32x4 acc[8];
  #pragma unroll
  for (int nt = 0; nt < 8; ++nt) acc[nt] = z4;
  #pragma unroll
  for (int kt = 0; kt < KTX; ++kt){
    #pragma unroll
    for (int nt = 0; nt < 8; ++nt)
      acc[nt] = MF(afX[kt], ldB(pk, offX + kt*8 + nt, lane), acc[nt]);
  }
  #pragma unroll
  for (int nt = 0; nt < 8; ++nt){
    float bv = bx[nt*16 + r15];
    float v0 = tanh_fast(acc[nt][0] + bv);
    float v1 = tanh_fast(acc[nt][1] + bv);
    float v2 = tanh_fast(acc[nt][2] + bv);
    float v3 = tanh_fast(acc[nt][3] + bv);
    xp[nt][0] = (unsigned)f2bf(v0) | ((unsigned)f2bf(v1) << 16);
    xp[nt][1] = (unsigned)f2bf(v2) | ((unsigned)f2bf(v3) << 16);
  }
  // dist2 = ||tanh(u@Wz)||^2
  f32x4 a2[4];
  #pragma unroll
  for (int nt = 0; nt < 4; ++nt) a2[nt] = z4;
  #pragma unroll
  for (int kt = 0; kt < KTZ; ++kt){
    #pragma unroll
    for (int nt = 0; nt < 4; ++nt)
      a2[nt] = MF(afZ[kt], ldB(pk, offZ + kt*4 + nt, lane), a2[nt]);
  }
  #pragma unroll
  for (int j = 0; j < 4; ++j){
    float s = 0.f;
    #pragma unroll
    for (int nt = 0; nt < 4; ++nt){ float t = tanh_fast(a2[nt][j]); s += t*t; }
    d2o[j] = s;
  }
  #pragma unroll
  for (int m = 1; m < 16; m <<= 1){
    #pragma unroll
    for (int j = 0; j < 4; ++j) d2o[j] += __shfl_xor(d2o[j], m);
  }
}

// ---------------- main kernel: no LDS, no barriers ----------------
__global__ __launch_bounds__(256) void reward_main(
    const float* __restrict__ z, const float* __restrict__ action,
    const float* __restrict__ rw, const float* __restrict__ control,
    const float* __restrict__ act_bx, const float* __restrict__ ctl_bx,
    const float* __restrict__ cht_bx, const float* __restrict__ consb,
    const float* __restrict__ formb,
    const unsigned short* __restrict__ packed, const float* __restrict__ prep,
    const float* __restrict__ sig, float* __restrict__ out)
{
  const int wid  = threadIdx.x >> 6;
  const int lane = threadIdx.x & 63;
  const int g0   = blockIdx.x*64 + wid*16;
  const int r15  = lane & 15;
  const int hi   = lane >> 4;
  const int ko   = hi << 3;
  const int arow = g0 + r15;
  const f32x4 z4 = {0.f,0.f,0.f,0.f};

  // ---- raw-input A-fragments ----
  s16x8 fz0 = ldA_g(z + (size_t)arow*64,            ko, 64);
  s16x8 fz1 = ldA_g(z + (size_t)arow*64 + 32,       ko, 32);
  s16x8 fac = ldA_g(action + (size_t)arow*32,       ko, 32);
  s16x8 fc0 = ldA_g(control + (size_t)arow*64,      ko, 64);
  s16x8 fc1 = ldA_g(control + (size_t)arow*64 + 32, ko, 32);
  s16x8 frw = ldA_g(rw + (size_t)arow*16,           ko, 16);

  // ---- tokenizers: x_t packed bf16 in regs, dist2 reduced ----
  unsigned xpk[3][8][2];
  float d2[3][4];
  {
    s16x8 afA[3] = {fac, fz0, fz1};
    token_reg<3,1>(packed, OFF_ACTX, afA, OFF_ACTZ, &fac, act_bx, lane, xpk[0], d2[0]);
  }
  {
    s16x8 afC[4] = {fc0, fc1, fz0, fz1};
    s16x8 afCz[2] = {fc0, fc1};
    token_reg<4,2>(packed, OFF_CTLX, afC, OFF_CTLZ, afCz, ctl_bx, lane, xpk[1], d2[1]);
  }
  {
    s16x8 afH[3] = {frw, fz0, fz1};
    token_reg<3,1>(packed, OFF_CHTX, afH, OFF_CHTZ, &frw, cht_bx, lane, xpk[2], d2[2]);
  }

  // ---- qW = z @ Weqk + bqk  (q pre-multiplied by Wk^T) ----
  f32x4 qw[8];
  {
    #pragma unroll
    for (int nt = 0; nt < 8; ++nt) qw[nt] = z4;
    s16x8 afE[2] = {fz0, fz1};
    #pragma unroll
    for (int kt = 0; kt < 2; ++kt)
      #pragma unroll
      for (int nt = 0; nt < 8; ++nt)
        qw[nt] = MF(afE[kt], ldB(packed, OFF_WEQK + kt*8 + nt, lane), qw[nt]);
    const float* bqk = prep + 16384;
    #pragma unroll
    for (int nt = 0; nt < 8; ++nt){
      float bv = bqk[nt*16 + r15];
      #pragma unroll
      for (int j = 0; j < 4; ++j) qw[nt][j] += bv;
    }
  }

  // ---- g = control @ WvofT  (form-head vector per row) ----
  f32x4 g[8];
  {
    #pragma unroll
    for (int nt = 0; nt < 8; ++nt) g[nt] = z4;
    s16x8 afG[2] = {fc0, fc1};
    #pragma unroll
    for (int kt = 0; kt < 2; ++kt)
      #pragma unroll
      for (int nt = 0; nt < 8; ++nt)
        g[nt] = MF(afG[kt], ldB(packed, OFF_WVOFT + kt*8 + nt, lane), g[nt]);
  }

  // ---- scores: s_t = (x_t . qW)/sqrt(M) - dist2_t  (lane-local dot) ----
  float sp[3][4];
  #pragma unroll
  for (int t = 0; t < 3; ++t){
    #pragma unroll
    for (int j = 0; j < 4; ++j) sp[t][j] = 0.f;
    #pragma unroll
    for (int nt = 0; nt < 8; ++nt){
      unsigned p0 = xpk[t][nt][0], p1 = xpk[t][nt][1];
      sp[t][0] += ubf_lo(p0)*qw[nt][0];
      sp[t][1] += ubf_hi(p0)*qw[nt][1];
      sp[t][2] += ubf_lo(p1)*qw[nt][2];
      sp[t][3] += ubf_hi(p1)*qw[nt][3];
    }
  }
  #pragma unroll
  for (int m = 1; m < 16; m <<= 1)
    #pragma unroll
    for (int t = 0; t < 3; ++t)
      #pragma unroll
      for (int j = 0; j < 4; ++j) sp[t][j] += __shfl_xor(sp[t][j], m);

  // ---- softmax (redundant per lane, no LDS) ----
  float at[3][4];
  #pragma unroll
  for (int j = 0; j < 4; ++j){
    const float isq = 0.0883883476483184f;
    float s0 = sp[0][j]*isq - d2[0][j];
    float s1 = sp[1][j]*isq - d2[1][j];
    float s2 = sp[2][j]*isq - d2[2][j];
    float mx = fmaxf(s0, fmaxf(s1, s2));
    float e0 = __expf(s0 - mx), e1 = __expf(s1 - mx), e2 = __expf(s2 - mx);
    float inv = 1.f/(e0 + e1 + e2);
    at[0][j] = e0*inv; at[1][j] = e1*inv; at[2][j] = e2*inv;
  }

  // ---- xbar = sum_t attn_t * x_t ----
  float xb[8][4];
  #pragma unroll
  for (int nt = 0; nt < 8; ++nt){
    #pragma unroll
    for (int j = 0; j < 4; ++j){
      unsigned p = xpk[0][nt][j>>1];
      float v = at[0][j] * ((j&1) ? ubf_hi(p) : ubf_lo(p));
      p = xpk[1][nt][j>>1];
      v += at[1][j] * ((j&1) ? ubf_hi(p) : ubf_lo(p));
      p = xpk[2][nt][j>>1];
      v += at[2][j] * ((j&1) ? ubf_hi(p) : ubf_lo(p));
      xb[nt][j] = v;
    }
  }

  // ---- heads: cons = xbar.wvoc ; form x control = xbar.g ----
  const float inv_f = sig[0], inv_c = sig[1], cb = consb[0];
  const float* wvoc = prep + 16512;
  float wv[8];
  #pragma unroll
  for (int nt = 0; nt < 8; ++nt) wv[nt] = wvoc[nt*16 + r15];

  float tot[4];
  #pragma unroll
  for (int j = 0; j < 4; ++j){
    float sc = 0.f, sg = 0.f;
    #pragma unroll
    for (int nt = 0; nt < 8; ++nt){
      sc += xb[nt][j]*wv[nt];
      sg += xb[nt][j]*g[nt][j];
    }
    tot[j] = inv_c*sc + inv_f*sg;
  }
  #pragma unroll
  for (int m = 1; m < 16; m <<= 1)
    #pragma unroll
    for (int j = 0; j < 4; ++j) tot[j] += __shfl_xor(tot[j], m);

  // ---- fb . control (A-pattern dot, f32 reload) ----
  float fbp = 0.f;
  {
    const float* cp = control + (size_t)arow*64;
    float4 c0a = *(const float4*)(cp + ko);
    float4 c0b = *(const float4*)(cp + ko + 4);
    float4 c1a = *(const float4*)(cp + 32 + ko);
    float4 c1b = *(const float4*)(cp + 32 + ko + 4);
    float4 f0a = *(const float4*)(formb + ko);
    float4 f0b = *(const float4*)(formb + ko + 4);
    float4 f1a = *(const float4*)(formb + 32 + ko);
    float4 f1b = *(const float4*)(formb + 32 + ko + 4);
    fbp = c0a.x*f0a.x + c0a.y*f0a.y + c0a.z*f0a.z + c0a.w*f0a.w
        + c0b.x*f0b.x + c0b.y*f0b.y + c0b.z*f0b.z + c0b.w*f0b.w
        + c1a.x*f1a.x + c1a.y*f1a.y + c1a.z*f1a.z + c1a.w*f1a.w
        + c1b.x*f1b.x + c1b.y*f1b.y + c1b.z*f1b.z + c1b.w*f1b.w;
  }
  fbp += __shfl_xor(fbp, 16);
  fbp += __shfl_xor(fbp, 32);          // all lanes: fbdot for row r15

  if (r15 == 0){
    #pragma unroll
    for (int j = 0; j < 4; ++j){
      float fbj = __shfl(fbp, hi*4 + j);
      out[g0 + hi*4 + j] = tot[j] + fbj + cb;
    }
  } else {
    // shfl must be executed by source lanes too
    #pragma unroll
    for (int j = 0; j < 4; ++j) (void)__shfl(fbp, hi*4 + j);
  }
}

extern "C" void kernel_launch(void* const* d_in, const int* in_sizes, int n_in,
                              void* d_out, int out_size, void* d_ws, size_t ws_size,
                              hipStream_t stream)
{
  const float* z      = (const float*)d_in[0];
  const float* action = (const float*)d_in[1];
  const float* rw     = (const float*)d_in[2];
  const float* control= (const float*)d_in[3];
  const float* actWx  = (const float*)d_in[4];
  const float* actbx  = (const float*)d_in[5];
  const float* actWz  = (const float*)d_in[6];
  const float* ctlWx  = (const float*)d_in[7];
  const float* ctlbx  = (const float*)d_in[8];
  const float* ctlWz  = (const float*)d_in[9];
  const float* chtWx  = (const float*)d_in[10];
  const float* chtbx  = (const float*)d_in[11];
  const float* chtWz  = (const float*)d_in[12];
  const float* We     = (const float*)d_in[13];
  const float* be     = (const float*)d_in[14];
  const float* Wq     = (const float*)d_in[15];
  const float* Wk     = (const float*)d_in[16];
  const float* Wv     = (const float*)d_in[17];
  const float* Wo     = (const float*)d_in[18];
  const float* consW  = (const float*)d_in[19];
  const float* consb  = (const float*)d_in[20];
  const float* formW  = (const float*)d_in[21];
  const float* formb  = (const float*)d_in[22];
  float* out = (float*)d_out;

  unsigned short* packed = (unsigned short*)d_ws;
  float* sig  = (float*)((char*)d_ws + SIG_OFF);
  float* prep = (float*)((char*)d_ws + PREP_OFF);

  hipLaunchKernelGGL(prep_sigma_k, dim3(131), dim3(1024), 0, stream,
                     We, be, Wq, Wk, Wv, Wo, consW, formW, prep, sig);
  hipLaunchKernelGGL(pack_k2, dim3(N_TILES), dim3(512), 0, stream,
                     actWx, ctlWx, chtWx, actWz, ctlWz, chtWz, prep, packed);
  hipLaunchKernelGGL(reward_main, dim3(32768/64), dim3(256), 0, stream,
                     z, action, rw, control, actbx, ctlbx, chtbx,
                     consb, formb, packed, prep, sig, out);
}

// Round 4
// 64.014 us; speedup vs baseline: 2.1637x; 1.0338x over previous
//
#include <hip/hip_runtime.h>
#include <hip/hip_bf16.h>

// RewardHead fused kernel for MI355X (gfx950) — round 4.
// B=32768, D=64, A=32, K=16, M=128. Output: [B,1] f32.
//
// vs round 3: (a) sigma block uses conflict-free column reads (b32 per-lane,
// float4 broadcasts) + only 3 norm-reductions; (b) reward_main stages all
// 128KB of packed B-fragments into LDS once per 512-thread block (1 block/CU),
// making every MFMA B-read a conflict-free ds_read_b128.

typedef float f32x4 __attribute__((ext_vector_type(4)));
typedef short s16x8 __attribute__((ext_vector_type(8)));

#define OFF_ACTX  0
#define OFF_CTLX  24
#define OFF_CHTX  56
#define OFF_ACTZ  80
#define OFF_CTLZ  84
#define OFF_CHTZ  92
#define OFF_WEQK  96
#define OFF_WVOFT 112
#define N_TILES   128
#define SIG_OFF   (N_TILES*1024)
#define PREP_OFF  (SIG_OFF + 256)

__device__ __forceinline__ unsigned short f2bf(float f){
  unsigned u = __float_as_uint(f);
  u += 0x7fffu + ((u>>16)&1u);          // RNE
  return (unsigned short)(u>>16);
}
__device__ __forceinline__ float ubf_lo(unsigned u){ return __uint_as_float(u<<16); }
__device__ __forceinline__ float ubf_hi(unsigned u){ return __uint_as_float(u & 0xffff0000u); }

union V8 { s16x8 v; unsigned short us[8]; uint4 q; };

__device__ __forceinline__ f32x4 MF(s16x8 a, s16x8 b, f32x4 c){
  return __builtin_amdgcn_mfma_f32_16x16x32_bf16(a, b, c, 0, 0, 0);
}

// B-fragment from LDS-staged packed tiles: one conflict-free ds_read_b128.
__device__ __forceinline__ s16x8 ldB(const unsigned short* pk, int tile, int lane){
  V8 t;
  t.q = *reinterpret_cast<const uint4*>(pk + ((tile<<6) + lane)*8);
  return t.v;
}

// A-fragment from global f32 row data (zero-fill when ko >= limit).
__device__ __forceinline__ s16x8 ldA_g(const float* __restrict__ p, int ko, int limit){
  V8 t;
  if (ko < limit){
    const float4* q4 = reinterpret_cast<const float4*>(p + ko);
    float4 a = q4[0], b = q4[1];
    t.us[0]=f2bf(a.x); t.us[1]=f2bf(a.y); t.us[2]=f2bf(a.z); t.us[3]=f2bf(a.w);
    t.us[4]=f2bf(b.x); t.us[5]=f2bf(b.y); t.us[6]=f2bf(b.z); t.us[7]=f2bf(b.w);
  } else {
    t.q = make_uint4(0u,0u,0u,0u);
  }
  return t.v;
}

__device__ __forceinline__ float tanh_fast(float x){
  x = fminf(15.f, fmaxf(-15.f, x));
  float e = __expf(2.f*x);
  return 1.f - __fdividef(2.f, e + 1.f);
}

// ---------------- prep (folded matrices) + sigma ----------------
// blocks 0..63: Weqk row d; block 64: bqk; blocks 65..128: WvofT row d;
// block 129: wvoc; block 130: spectral norms.
__device__ __forceinline__ float frob_reduce(float a0,float a1,float a2,float a3,
                                             float* red, int w, int l){
  float nr = a0*a0+a1*a1+a2*a2+a3*a3;
  #pragma unroll
  for (int m = 1; m < 64; m <<= 1) nr += __shfl_xor(nr, m);
  if (l == 0) red[w] = nr;
  __syncthreads();
  float tot = 0.f;
  #pragma unroll
  for (int k = 0; k < 16; ++k) tot += red[k];
  return sqrtf(tot);
}

__global__ __launch_bounds__(1024) void prep_sigma_k(
    const float* __restrict__ We, const float* __restrict__ be,
    const float* __restrict__ Wq, const float* __restrict__ Wk,
    const float* __restrict__ Wv, const float* __restrict__ Wo,
    const float* __restrict__ consW, const float* __restrict__ formW,
    float* __restrict__ prep, float* __restrict__ sig)
{
  __shared__ float tsh[128];
  __shared__ float Ws[128][68];   // Ws[m][d] = formW[m][d] (row-major, stride 68)
  __shared__ float Ra[64][68];
  __shared__ float Rb[64][68];
  __shared__ float red[16];
  __shared__ float cons_s;
  const int b = blockIdx.x;
  const int tid = threadIdx.x;

  if (b < 130){
    if (b <= 64){
      const float* rowv = (b == 64) ? be : (We + (size_t)b*128);
      if (tid < 128){
        float s = 0.f;
        for (int m = 0; m < 128; ++m) s += rowv[m]*Wq[(size_t)m*128 + tid];
        tsh[tid] = s;
      }
      __syncthreads();
      if (tid < 128){
        float s = 0.f;
        for (int p = 0; p < 128; ++p) s += tsh[p]*Wk[(size_t)tid*128 + p];
        if (b == 64) prep[16384 + tid] = s;
        else         prep[(size_t)b*128 + tid] = s;
      }
    } else {
      int d = b - 65;                        // 0..63 WvofT row d; 64 -> wvoc
      if (tid < 128){
        float s = 0.f;
        if (d < 64){ for (int j = 0; j < 128; ++j) s += Wo[(size_t)tid*128 + j]*formW[(size_t)j*64 + d]; }
        else       { for (int j = 0; j < 128; ++j) s += Wo[(size_t)tid*128 + j]*consW[j]; }
        tsh[tid] = s;
      }
      __syncthreads();
      if (tid < 128){
        float s = 0.f;
        for (int p = 0; p < 128; ++p) s += Wv[(size_t)tid*128 + p]*tsh[p];
        if (d < 64) prep[8192 + (size_t)d*128 + tid] = s;
        else        prep[16512 + tid] = s;
      }
    }
    return;
  }

  // ---- block 130: sigma. G = W^T W; 6 squarings, norms at {0,3,6}. ----
  const int w = tid >> 6, l = tid & 63;
  const int i0 = w << 2;

  for (int idx = tid; idx < 8192; idx += 1024)
    Ws[idx >> 6][idx & 63] = formW[idx];

  if (w == 15){
    float c0 = consW[l], c1 = consW[l + 64];
    float s = c0*c0 + c1*c1;
    #pragma unroll
    for (int m = 1; m < 64; m <<= 1) s += __shfl_xor(s, m);
    if (l == 0) cons_s = s;
  }
  __syncthreads();

  // G rows i0..i0+3, lane l = column: per-lane b32 column reads (conflict-free)
  // + float4 broadcast of Ws[m][i0..i0+3].
  float a0=0.f,a1=0.f,a2=0.f,a3=0.f;
  #pragma unroll 8
  for (int m = 0; m < 128; ++m){
    float xl = Ws[m][l];
    float4 bi = *(const float4*)&Ws[m][i0];
    a0 += bi.x*xl; a1 += bi.y*xl; a2 += bi.z*xl; a3 += bi.w*xl;
  }
  float n0 = frob_reduce(a0,a1,a2,a3, red, w, l);
  {
    float iv = 1.f/n0;
    Ra[i0+0][l]=a0*iv; Ra[i0+1][l]=a1*iv; Ra[i0+2][l]=a2*iv; Ra[i0+3][l]=a3*iv;
  }
  __syncthreads();

  float n3 = 1.f, n6 = 1.f;
  float (*S)[68] = Ra;
  float (*D)[68] = Rb;
  for (int s = 1; s <= 6; ++s){
    a0=0.f; a1=0.f; a2=0.f; a3=0.f;
    #pragma unroll 4
    for (int m4 = 0; m4 < 64; m4 += 4){
      float x0 = S[m4+0][l], x1 = S[m4+1][l], x2 = S[m4+2][l], x3 = S[m4+3][l];
      float4 b0 = *(const float4*)&S[i0+0][m4];
      float4 b1 = *(const float4*)&S[i0+1][m4];
      float4 b2 = *(const float4*)&S[i0+2][m4];
      float4 b3 = *(const float4*)&S[i0+3][m4];
      a0 += b0.x*x0 + b0.y*x1 + b0.z*x2 + b0.w*x3;
      a1 += b1.x*x0 + b1.y*x1 + b1.z*x2 + b1.w*x3;
      a2 += b2.x*x0 + b2.y*x1 + b2.z*x2 + b2.w*x3;
      a3 += b3.x*x0 + b3.y*x1 + b3.z*x2 + b3.w*x3;
    }
    if (s == 3){
      n3 = frob_reduce(a0,a1,a2,a3, red, w, l);
      float iv = 1.f/n3;
      D[i0+0][l]=a0*iv; D[i0+1][l]=a1*iv; D[i0+2][l]=a2*iv; D[i0+3][l]=a3*iv;
    } else if (s == 6){
      n6 = frob_reduce(a0,a1,a2,a3, red, w, l);
    } else {
      D[i0+0][l]=a0; D[i0+1][l]=a1; D[i0+2][l]=a2; D[i0+3][l]=a3;
    }
    __syncthreads();
    float (*tmp)[68] = S; S = D; D = tmp;
  }

  if (tid == 0){
    // ||G^64||_F = n0^64 * n3^8 * n6  ->  sigma = ||.||^(1/128)
    float sf = expf(0.5f*logf(n0) + 0.0625f*logf(n3) + 0.0078125f*logf(n6));
    sig[0] = 1.f/(sf + 1e-6f);
    sig[1] = 1.f/(sqrtf(cons_s) + 1e-6f);
  }
}

// ---------------- weight pre-pack (128 tiles) ----------------
__global__ __launch_bounds__(512) void pack_k2(
    const float* __restrict__ aWx, const float* __restrict__ cWx, const float* __restrict__ hWx,
    const float* __restrict__ aWz, const float* __restrict__ cWz, const float* __restrict__ hWz,
    const float* __restrict__ prep, unsigned short* __restrict__ packed)
{
  int tile = blockIdx.x;
  const float* W; int N; int kind = 0; int base;
  if      (tile < 24) { W=aWx;        N=128; base=OFF_ACTX; }
  else if (tile < 56) { W=cWx;        N=128; base=OFF_CTLX; }
  else if (tile < 80) { W=hWx;        N=128; base=OFF_CHTX; kind=1; }
  else if (tile < 84) { W=aWz;        N=64;  base=OFF_ACTZ; }
  else if (tile < 92) { W=cWz;        N=64;  base=OFF_CTLZ; }
  else if (tile < 96) { W=hWz;        N=64;  base=OFF_CHTZ; kind=2; }
  else if (tile < 112){ W=prep;       N=128; base=OFF_WEQK; }
  else                { W=prep+8192;  N=128; base=OFF_WVOFT; }
  int NT = N >> 4;
  int lt = tile - base;
  int nt = lt % NT, kt = lt / NT;
  int tid = threadIdx.x;
  int lane = tid >> 3, i = tid & 7;
  int k = kt*32 + ((lane>>4)<<3) + i;
  int n = nt*16 + (lane & 15);
  int sr = k;
  if (kind == 1) sr = (k < 16) ? k : (k < 32 ? -1 : k - 16);
  else if (kind == 2) sr = (k < 16) ? k : -1;
  float v = (sr >= 0) ? W[(size_t)sr*N + n] : 0.f;
  packed[(((size_t)tile<<6) + lane)*8 + i] = f2bf(v);
}

// ---------------- tokenizer (pure registers) ----------------
template<int KTX, int KTZ>
__device__ __forceinline__ void token_reg(
    const unsigned short* pk, int offX, const s16x8* afX,
    int offZ, const s16x8* afZ, const float* __restrict__ bx,
    int lane, unsigned xp[8][2], float d2o[4])
{
  const int r15 = lane & 15;
  const f32x4 z4 = {0.f,0.f,0.f,0.f};
  f32x4 acc[8];
  #pragma unroll
  for (int nt = 0; nt < 8; ++nt) acc[nt] = z4;
  #pragma unroll
  for (int kt = 0; kt < KTX; ++kt){
    #pragma unroll
    for (int nt = 0; nt < 8; ++nt)
      acc[nt] = MF(afX[kt], ldB(pk, offX + kt*8 + nt, lane), acc[nt]);
  }
  #pragma unroll
  for (int nt = 0; nt < 8; ++nt){
    float bv = bx[nt*16 + r15];
    float v0 = tanh_fast(acc[nt][0] + bv);
    float v1 = tanh_fast(acc[nt][1] + bv);
    float v2 = tanh_fast(acc[nt][2] + bv);
    float v3 = tanh_fast(acc[nt][3] + bv);
    xp[nt][0] = (unsigned)f2bf(v0) | ((unsigned)f2bf(v1) << 16);
    xp[nt][1] = (unsigned)f2bf(v2) | ((unsigned)f2bf(v3) << 16);
  }
  // dist2 = ||tanh(u@Wz)||^2
  f32x4 a2[4];
  #pragma unroll
  for (int nt = 0; nt < 4; ++nt) a2[nt] = z4;
  #pragma unroll
  for (int kt = 0; kt < KTZ; ++kt){
    #pragma unroll
    for (int nt = 0; nt < 4; ++nt)
      a2[nt] = MF(afZ[kt], ldB(pk, offZ + kt*4 + nt, lane), a2[nt]);
  }
  #pragma unroll
  for (int j = 0; j < 4; ++j){
    float s = 0.f;
    #pragma unroll
    for (int nt = 0; nt < 4; ++nt){ float t = tanh_fast(a2[nt][j]); s += t*t; }
    d2o[j] = s;
  }
  #pragma unroll
  for (int m = 1; m < 16; m <<= 1){
    #pragma unroll
    for (int j = 0; j < 4; ++j) d2o[j] += __shfl_xor(d2o[j], m);
  }
}

// ---------------- main kernel: LDS-staged weights, 8 waves/block ----------------
__global__ __launch_bounds__(512, 2) void reward_main(
    const float* __restrict__ z, const float* __restrict__ action,
    const float* __restrict__ rw, const float* __restrict__ control,
    const float* __restrict__ act_bx, const float* __restrict__ ctl_bx,
    const float* __restrict__ cht_bx, const float* __restrict__ consb,
    const float* __restrict__ formb,
    const unsigned short* __restrict__ packed, const float* __restrict__ prep,
    const float* __restrict__ sig, float* __restrict__ out)
{
  __shared__ unsigned short pk_sh[65536];   // all 128 packed tiles (128 KB)

  const int tid  = threadIdx.x;
  const int wid  = tid >> 6;
  const int lane = tid & 63;
  const int g0   = blockIdx.x*128 + wid*16;
  const int r15  = lane & 15;
  const int hi   = lane >> 4;
  const int ko   = hi << 3;
  const int arow = g0 + r15;
  const f32x4 z4 = {0.f,0.f,0.f,0.f};

  // ---- stage packed weights global -> LDS (one shot, coalesced) ----
  {
    uint4* d4 = reinterpret_cast<uint4*>(pk_sh);
    const uint4* s4 = reinterpret_cast<const uint4*>(packed);
    #pragma unroll
    for (int it = 0; it < 16; ++it)
      d4[it*512 + tid] = s4[it*512 + tid];
  }
  __syncthreads();
  const unsigned short* pk = pk_sh;

  // ---- raw-input A-fragments ----
  s16x8 fz0 = ldA_g(z + (size_t)arow*64,            ko, 64);
  s16x8 fz1 = ldA_g(z + (size_t)arow*64 + 32,       ko, 32);
  s16x8 fac = ldA_g(action + (size_t)arow*32,       ko, 32);
  s16x8 fc0 = ldA_g(control + (size_t)arow*64,      ko, 64);
  s16x8 fc1 = ldA_g(control + (size_t)arow*64 + 32, ko, 32);
  s16x8 frw = ldA_g(rw + (size_t)arow*16,           ko, 16);

  // ---- tokenizers: x_t packed bf16 in regs, dist2 reduced ----
  unsigned xpk[3][8][2];
  float d2[3][4];
  {
    s16x8 afA[3] = {fac, fz0, fz1};
    token_reg<3,1>(pk, OFF_ACTX, afA, OFF_ACTZ, &fac, act_bx, lane, xpk[0], d2[0]);
  }
  {
    s16x8 afC[4] = {fc0, fc1, fz0, fz1};
    s16x8 afCz[2] = {fc0, fc1};
    token_reg<4,2>(pk, OFF_CTLX, afC, OFF_CTLZ, afCz, ctl_bx, lane, xpk[1], d2[1]);
  }
  {
    s16x8 afH[3] = {frw, fz0, fz1};
    token_reg<3,1>(pk, OFF_CHTX, afH, OFF_CHTZ, &frw, cht_bx, lane, xpk[2], d2[2]);
  }

  // ---- qW = z @ Weqk + bqk ----
  f32x4 qw[8];
  {
    #pragma unroll
    for (int nt = 0; nt < 8; ++nt) qw[nt] = z4;
    s16x8 afE[2] = {fz0, fz1};
    #pragma unroll
    for (int kt = 0; kt < 2; ++kt)
      #pragma unroll
      for (int nt = 0; nt < 8; ++nt)
        qw[nt] = MF(afE[kt], ldB(pk, OFF_WEQK + kt*8 + nt, lane), qw[nt]);
    const float* bqk = prep + 16384;
    #pragma unroll
    for (int nt = 0; nt < 8; ++nt){
      float bv = bqk[nt*16 + r15];
      #pragma unroll
      for (int j = 0; j < 4; ++j) qw[nt][j] += bv;
    }
  }

  // ---- g = control @ WvofT ----
  f32x4 g[8];
  {
    #pragma unroll
    for (int nt = 0; nt < 8; ++nt) g[nt] = z4;
    s16x8 afG[2] = {fc0, fc1};
    #pragma unroll
    for (int kt = 0; kt < 2; ++kt)
      #pragma unroll
      for (int nt = 0; nt < 8; ++nt)
        g[nt] = MF(afG[kt], ldB(pk, OFF_WVOFT + kt*8 + nt, lane), g[nt]);
  }

  // ---- scores: s_t = (x_t . qW)/sqrt(M) - dist2_t ----
  float sp[3][4];
  #pragma unroll
  for (int t = 0; t < 3; ++t){
    #pragma unroll
    for (int j = 0; j < 4; ++j) sp[t][j] = 0.f;
    #pragma unroll
    for (int nt = 0; nt < 8; ++nt){
      unsigned p0 = xpk[t][nt][0], p1 = xpk[t][nt][1];
      sp[t][0] += ubf_lo(p0)*qw[nt][0];
      sp[t][1] += ubf_hi(p0)*qw[nt][1];
      sp[t][2] += ubf_lo(p1)*qw[nt][2];
      sp[t][3] += ubf_hi(p1)*qw[nt][3];
    }
  }
  #pragma unroll
  for (int m = 1; m < 16; m <<= 1)
    #pragma unroll
    for (int t = 0; t < 3; ++t)
      #pragma unroll
      for (int j = 0; j < 4; ++j) sp[t][j] += __shfl_xor(sp[t][j], m);

  // ---- softmax (redundant per lane) ----
  float at[3][4];
  #pragma unroll
  for (int j = 0; j < 4; ++j){
    const float isq = 0.0883883476483184f;
    float s0 = sp[0][j]*isq - d2[0][j];
    float s1 = sp[1][j]*isq - d2[1][j];
    float s2 = sp[2][j]*isq - d2[2][j];
    float mx = fmaxf(s0, fmaxf(s1, s2));
    float e0 = __expf(s0 - mx), e1 = __expf(s1 - mx), e2 = __expf(s2 - mx);
    float inv = 1.f/(e0 + e1 + e2);
    at[0][j] = e0*inv; at[1][j] = e1*inv; at[2][j] = e2*inv;
  }

  // ---- xbar = sum_t attn_t * x_t ----
  float xb[8][4];
  #pragma unroll
  for (int nt = 0; nt < 8; ++nt){
    #pragma unroll
    for (int j = 0; j < 4; ++j){
      unsigned p = xpk[0][nt][j>>1];
      float v = at[0][j] * ((j&1) ? ubf_hi(p) : ubf_lo(p));
      p = xpk[1][nt][j>>1];
      v += at[1][j] * ((j&1) ? ubf_hi(p) : ubf_lo(p));
      p = xpk[2][nt][j>>1];
      v += at[2][j] * ((j&1) ? ubf_hi(p) : ubf_lo(p));
      xb[nt][j] = v;
    }
  }

  // ---- heads ----
  const float inv_f = sig[0], inv_c = sig[1], cb = consb[0];
  const float* wvoc = prep + 16512;
  float wv[8];
  #pragma unroll
  for (int nt = 0; nt < 8; ++nt) wv[nt] = wvoc[nt*16 + r15];

  float tot[4];
  #pragma unroll
  for (int j = 0; j < 4; ++j){
    float sc = 0.f, sg = 0.f;
    #pragma unroll
    for (int nt = 0; nt < 8; ++nt){
      sc += xb[nt][j]*wv[nt];
      sg += xb[nt][j]*g[nt][j];
    }
    tot[j] = inv_c*sc + inv_f*sg;
  }
  #pragma unroll
  for (int m = 1; m < 16; m <<= 1)
    #pragma unroll
    for (int j = 0; j < 4; ++j) tot[j] += __shfl_xor(tot[j], m);

  // ---- fb . control (f32, L1-hot reload) ----
  float fbp = 0.f;
  {
    const float* cp = control + (size_t)arow*64;
    float4 c0a = *(const float4*)(cp + ko);
    float4 c0b = *(const float4*)(cp + ko + 4);
    float4 c1a = *(const float4*)(cp + 32 + ko);
    float4 c1b = *(const float4*)(cp + 32 + ko + 4);
    float4 f0a = *(const float4*)(formb + ko);
    float4 f0b = *(const float4*)(formb + ko + 4);
    float4 f1a = *(const float4*)(formb + 32 + ko);
    float4 f1b = *(const float4*)(formb + 32 + ko + 4);
    fbp = c0a.x*f0a.x + c0a.y*f0a.y + c0a.z*f0a.z + c0a.w*f0a.w
        + c0b.x*f0b.x + c0b.y*f0b.y + c0b.z*f0b.z + c0b.w*f0b.w
        + c1a.x*f1a.x + c1a.y*f1a.y + c1a.z*f1a.z + c1a.w*f1a.w
        + c1b.x*f1b.x + c1b.y*f1b.y + c1b.z*f1b.z + c1b.w*f1b.w;
  }
  fbp += __shfl_xor(fbp, 16);
  fbp += __shfl_xor(fbp, 32);          // all lanes: fb.control for row r15

  float fbj[4];
  #pragma unroll
  for (int j = 0; j < 4; ++j) fbj[j] = __shfl(fbp, hi*4 + j);
  if (r15 == 0){
    #pragma unroll
    for (int j = 0; j < 4; ++j) out[g0 + hi*4 + j] = tot[j] + fbj[j] + cb;
  }
}

extern "C" void kernel_launch(void* const* d_in, const int* in_sizes, int n_in,
                              void* d_out, int out_size, void* d_ws, size_t ws_size,
                              hipStream_t stream)
{
  const float* z      = (const float*)d_in[0];
  const float* action = (const float*)d_in[1];
  const float* rw     = (const float*)d_in[2];
  const float* control= (const float*)d_in[3];
  const float* actWx  = (const float*)d_in[4];
  const float* actbx  = (const float*)d_in[5];
  const float* actWz  = (const float*)d_in[6];
  const float* ctlWx  = (const float*)d_in[7];
  const float* ctlbx  = (const float*)d_in[8];
  const float* ctlWz  = (const float*)d_in[9];
  const float* chtWx  = (const float*)d_in[10];
  const float* chtbx  = (const float*)d_in[11];
  const float* chtWz  = (const float*)d_in[12];
  const float* We     = (const float*)d_in[13];
  const float* be     = (const float*)d_in[14];
  const float* Wq     = (const float*)d_in[15];
  const float* Wk     = (const float*)d_in[16];
  const float* Wv     = (const float*)d_in[17];
  const float* Wo     = (const float*)d_in[18];
  const float* consW  = (const float*)d_in[19];
  const float* consb  = (const float*)d_in[20];
  const float* formW  = (const float*)d_in[21];
  const float* formb  = (const float*)d_in[22];
  float* out = (float*)d_out;

  unsigned short* packed = (unsigned short*)d_ws;
  float* sig  = (float*)((char*)d_ws + SIG_OFF);
  float* prep = (float*)((char*)d_ws + PREP_OFF);

  hipLaunchKernelGGL(prep_sigma_k, dim3(131), dim3(1024), 0, stream,
                     We, be, Wq, Wk, Wv, Wo, consW, formW, prep, sig);
  hipLaunchKernelGGL(pack_k2, dim3(N_TILES), dim3(512), 0, stream,
                     actWx, ctlWx, chtWx, actWz, ctlWz, chtWz, prep, packed);
  hipLaunchKernelGGL(reward_main, dim3(256), dim3(512), 0, stream,
                     z, action, rw, control, actbx, ctlbx, chtbx,
                     consb, formb, packed, prep, sig, out);
}

// Round 5
// 41.850 us; speedup vs baseline: 3.3095x; 1.5296x over previous
//
#include <hip/hip_runtime.h>
#include <hip/hip_bf16.h>

// RewardHead fused kernel for MI355X (gfx950) — round 5.
// B=32768, D=64, A=32, K=16, M=128. Output: [B,1] f32.
//
// Two kernels:
//  prep_all (227 blocks x 256):
//    blocks 0..129  : fold rows Weqk/bqk/WvofT/wvoc (f32 VALU, global reads);
//                     Weqk/WvofT rows written DIRECTLY into packed bf16 tiles.
//    block  130     : spectral norms via 1-wave MFMA squaring chain
//                     (G=W^T W, 6 normalized squarings, Frobenius-root).
//    blocks 131..226: pack tokenizer weight tiles (0..95) f32->bf16.
//  reward_main (256 blocks x 512): unchanged round-4 kernel (LDS-staged
//    weights, folded linear algebra, no barriers after staging).
//
// d_ws: [0,128KB) packed bf16 B-fragments (128 tiles x 1KB)
//       [128KB,+8) sig; [128KB+256,...) prep f32: bqk@16384, wvoc@16512

typedef float f32x4 __attribute__((ext_vector_type(4)));
typedef short s16x8 __attribute__((ext_vector_type(8)));

#define OFF_ACTX  0
#define OFF_CTLX  24
#define OFF_CHTX  56
#define OFF_ACTZ  80
#define OFF_CTLZ  84
#define OFF_CHTZ  92
#define OFF_WEQK  96
#define OFF_WVOFT 112
#define N_TILES   128
#define SIG_OFF   (N_TILES*1024)
#define PREP_OFF  (SIG_OFF + 256)

__device__ __forceinline__ unsigned short f2bf(float f){
  unsigned u = __float_as_uint(f);
  u += 0x7fffu + ((u>>16)&1u);          // RNE
  return (unsigned short)(u>>16);
}
__device__ __forceinline__ float ubf_lo(unsigned u){ return __uint_as_float(u<<16); }
__device__ __forceinline__ float ubf_hi(unsigned u){ return __uint_as_float(u & 0xffff0000u); }

union V8 { s16x8 v; unsigned short us[8]; uint4 q; };

__device__ __forceinline__ f32x4 MF(s16x8 a, s16x8 b, f32x4 c){
  return __builtin_amdgcn_mfma_f32_16x16x32_bf16(a, b, c, 0, 0, 0);
}

__device__ __forceinline__ s16x8 ldB(const unsigned short* pk, int tile, int lane){
  V8 t;
  t.q = *reinterpret_cast<const uint4*>(pk + ((tile<<6) + lane)*8);
  return t.v;
}

__device__ __forceinline__ s16x8 ldA_g(const float* __restrict__ p, int ko, int limit){
  V8 t;
  if (ko < limit){
    const float4* q4 = reinterpret_cast<const float4*>(p + ko);
    float4 a = q4[0], b = q4[1];
    t.us[0]=f2bf(a.x); t.us[1]=f2bf(a.y); t.us[2]=f2bf(a.z); t.us[3]=f2bf(a.w);
    t.us[4]=f2bf(b.x); t.us[5]=f2bf(b.y); t.us[6]=f2bf(b.z); t.us[7]=f2bf(b.w);
  } else {
    t.q = make_uint4(0u,0u,0u,0u);
  }
  return t.v;
}

__device__ __forceinline__ float tanh_fast(float x){
  x = fminf(15.f, fmaxf(-15.f, x));
  float e = __expf(2.f*x);
  return 1.f - __fdividef(2.f, e + 1.f);
}

// ---------------- prep_all ----------------
__global__ __launch_bounds__(256) void prep_all(
    const float* __restrict__ We, const float* __restrict__ be,
    const float* __restrict__ Wq, const float* __restrict__ Wk,
    const float* __restrict__ Wv, const float* __restrict__ Wo,
    const float* __restrict__ consW, const float* __restrict__ formW,
    const float* __restrict__ aWx, const float* __restrict__ cWx,
    const float* __restrict__ hWx, const float* __restrict__ aWz,
    const float* __restrict__ cWz, const float* __restrict__ hWz,
    unsigned short* __restrict__ packed, float* __restrict__ prep,
    float* __restrict__ sig)
{
  const int b = blockIdx.x;
  const int tid = threadIdx.x;

  if (b < 130){
    // ---- fold rows (f32). Row r of Weqk/WvofT -> packed tile scatter. ----
    __shared__ float tsh[128];
    float s1 = 0.f;
    if (b <= 64){
      const float* rowv = (b == 64) ? be : (We + (size_t)b*128);
      if (tid < 128){
        float s = 0.f;
        for (int m = 0; m < 128; ++m) s += rowv[m]*Wq[(size_t)m*128 + tid];
        tsh[tid] = s;
      }
      __syncthreads();
      if (tid < 128){
        for (int p = 0; p < 128; ++p) s1 += tsh[p]*Wk[(size_t)tid*128 + p];
        if (b == 64) prep[16384 + tid] = s1;
        else {
          int r = b;
          int T = OFF_WEQK + ((r>>5)<<3) + (tid>>4);
          int l2 = (((r&31)>>3)<<4) | (tid&15);
          packed[((size_t)T*64 + l2)*8 + (r&7)] = f2bf(s1);
        }
      }
    } else {
      int d = b - 65;                        // 0..63: WvofT row d; 64: wvoc
      if (tid < 128){
        float s = 0.f;
        if (d < 64){ for (int j = 0; j < 128; ++j) s += Wo[(size_t)tid*128 + j]*formW[(size_t)j*64 + d]; }
        else       { for (int j = 0; j < 128; ++j) s += Wo[(size_t)tid*128 + j]*consW[j]; }
        tsh[tid] = s;
      }
      __syncthreads();
      if (tid < 128){
        for (int p = 0; p < 128; ++p) s1 += Wv[(size_t)tid*128 + p]*tsh[p];
        if (d < 64){
          int r = d;
          int T = OFF_WVOFT + ((r>>5)<<3) + (tid>>4);
          int l2 = (((r&31)>>3)<<4) | (tid&15);
          packed[((size_t)T*64 + l2)*8 + (r&7)] = f2bf(s1);
        } else prep[16512 + tid] = s1;
      }
    }
    return;
  }

  if (b == 130){
    // ---- spectral norms: 1-wave MFMA squaring chain ----
    __shared__ unsigned short SW[8192];   // W (128x64) in B-frag layout, 16 tiles
    __shared__ unsigned short SG[4096];   // G (64x64)  in B-frag layout, 8 tiles

    // pack formW -> SW (all 256 threads, 4 (tile,lane)-slots each)
    #pragma unroll
    for (int s4 = 0; s4 < 4; ++s4){
      int q = tid*4 + s4;                 // 0..1023
      int T = q >> 6, l = q & 63;
      V8 t;
      #pragma unroll
      for (int i = 0; i < 8; ++i){
        int k = (T>>2)*32 + ((l>>4)<<3) + i;
        int n = ((T&3)<<4) + (l&15);
        t.us[i] = f2bf(formW[(size_t)k*64 + n]);
      }
      *reinterpret_cast<uint4*>(&SW[q*8]) = t.q;
    }
    __syncthreads();
    if (tid >= 64) return;
    const int l = tid;
    const f32x4 z4 = {0.f,0.f,0.f,0.f};

    // cons_W 2-norm
    float cs;
    { float c0 = consW[l], c1 = consW[l+64];
      cs = c0*c0 + c1*c1;
      #pragma unroll
      for (int m = 1; m < 64; m <<= 1) cs += __shfl_xor(cs, m);
    }

    // G = W^T W : A-frag(it,kt) == SW tile(kt,it); B-frag(kt,nt) == SW tile(kt,nt)
    s16x8 wf[4][4];
    #pragma unroll
    for (int kt = 0; kt < 4; ++kt)
      #pragma unroll
      for (int x = 0; x < 4; ++x)
        wf[kt][x] = *reinterpret_cast<const s16x8*>(&SW[((((kt<<2)+x)<<6) | l)*8]);

    f32x4 D[4][4];
    #pragma unroll
    for (int it = 0; it < 4; ++it)
      #pragma unroll
      for (int nt = 0; nt < 4; ++nt){
        f32x4 a = z4;
        #pragma unroll
        for (int kt = 0; kt < 4; ++kt) a = MF(wf[kt][it], wf[kt][nt], a);
        D[it][nt] = a;
      }

    float L;
    {
      float ss = 0.f;
      #pragma unroll
      for (int it = 0; it < 4; ++it)
        #pragma unroll
        for (int nt = 0; nt < 4; ++nt)
          #pragma unroll
          for (int j = 0; j < 4; ++j) ss += D[it][nt][j]*D[it][nt][j];
      #pragma unroll
      for (int m = 1; m < 64; m <<= 1) ss += __shfl_xor(ss, m);
      float n0 = sqrtf(ss);
      L = logf(n0);
      float iv = 1.f/n0;
      // store D*iv -> SG (B-frag layout; rows of D-tile map to (ktg, i''))
      #pragma unroll
      for (int it = 0; it < 4; ++it){
        int rb  = it*16 + ((l>>4)<<2);
        int lp  = (((rb&31)>>3)<<4) | (l&15);
        int ib  = rb & 7;                  // 0 or 4
        int ktg = rb >> 5;
        #pragma unroll
        for (int nt = 0; nt < 4; ++nt){
          unsigned w0 = (unsigned)f2bf(D[it][nt][0]*iv) | ((unsigned)f2bf(D[it][nt][1]*iv)<<16);
          unsigned w1 = (unsigned)f2bf(D[it][nt][2]*iv) | ((unsigned)f2bf(D[it][nt][3]*iv)<<16);
          uint2 u; u.x = w0; u.y = w1;
          *reinterpret_cast<uint2*>(&SG[((((ktg<<2)+nt)<<6 | lp))*8 + ib]) = u;
        }
      }
    }

    // 6 normalized squarings: G symmetric -> A-frag(it,kt) == SG tile(kt,it)
    for (int s = 1; s <= 6; ++s){
      s16x8 gf[2][4];
      #pragma unroll
      for (int kt = 0; kt < 2; ++kt)
        #pragma unroll
        for (int x = 0; x < 4; ++x)
          gf[kt][x] = *reinterpret_cast<const s16x8*>(&SG[((((kt<<2)+x)<<6) | l)*8]);
      f32x4 E[4][4];
      #pragma unroll
      for (int it = 0; it < 4; ++it)
        #pragma unroll
        for (int nt = 0; nt < 4; ++nt){
          f32x4 a = MF(gf[0][it], gf[0][nt], z4);
          E[it][nt] = MF(gf[1][it], gf[1][nt], a);
        }
      float ss = 0.f;
      #pragma unroll
      for (int it = 0; it < 4; ++it)
        #pragma unroll
        for (int nt = 0; nt < 4; ++nt)
          #pragma unroll
          for (int j = 0; j < 4; ++j) ss += E[it][nt][j]*E[it][nt][j];
      #pragma unroll
      for (int m = 1; m < 64; m <<= 1) ss += __shfl_xor(ss, m);
      float ns = sqrtf(ss);
      L = 2.f*L + logf(ns);
      if (s < 6){
        float iv = 1.f/ns;
        #pragma unroll
        for (int it = 0; it < 4; ++it){
          int rb  = it*16 + ((l>>4)<<2);
          int lp  = (((rb&31)>>3)<<4) | (l&15);
          int ib  = rb & 7;
          int ktg = rb >> 5;
          #pragma unroll
          for (int nt = 0; nt < 4; ++nt){
            unsigned w0 = (unsigned)f2bf(E[it][nt][0]*iv) | ((unsigned)f2bf(E[it][nt][1]*iv)<<16);
            unsigned w1 = (unsigned)f2bf(E[it][nt][2]*iv) | ((unsigned)f2bf(E[it][nt][3]*iv)<<16);
            uint2 u; u.x = w0; u.y = w1;
            *reinterpret_cast<uint2*>(&SG[((((ktg<<2)+nt)<<6 | lp))*8 + ib]) = u;
          }
        }
      }
    }

    if (l == 0){
      // ln||G^64||_F = 64 ln n0 + 32 ln n1 + ... + ln n6 ; sigma = exp(L/128)
      float sf = expf(L*(1.f/128.f));
      sig[0] = 1.f/(sf + 1e-6f);
      sig[1] = 1.f/(sqrtf(cs) + 1e-6f);
    }
    return;
  }

  // ---- blocks 131..226: pack tokenizer tiles 0..95 ----
  {
    int tile = b - 131;
    const float* W; int N; int kind = 0; int base;
    if      (tile < 24) { W=aWx; N=128; base=OFF_ACTX; }
    else if (tile < 56) { W=cWx; N=128; base=OFF_CTLX; }
    else if (tile < 80) { W=hWx; N=128; base=OFF_CHTX; kind=1; }
    else if (tile < 84) { W=aWz; N=64;  base=OFF_ACTZ; }
    else if (tile < 92) { W=cWz; N=64;  base=OFF_CTLZ; }
    else                { W=hWz; N=64;  base=OFF_CHTZ; kind=2; }
    int NT = N >> 4;
    int lt = tile - base;
    int nt = lt % NT, kt = lt / NT;
    int l = tid >> 2, i0 = (tid & 3)*2;
    unsigned short us2[2];
    #pragma unroll
    for (int di = 0; di < 2; ++di){
      int i = i0 + di;
      int k = kt*32 + ((l>>4)<<3) + i;
      int n = nt*16 + (l & 15);
      int sr = k;
      if (kind == 1) sr = (k < 16) ? k : (k < 32 ? -1 : k - 16);
      else if (kind == 2) sr = (k < 16) ? k : -1;
      float v = (sr >= 0) ? W[(size_t)sr*N + n] : 0.f;
      us2[di] = f2bf(v);
    }
    *reinterpret_cast<unsigned*>(&packed[((size_t)tile*64 + l)*8 + i0]) =
        (unsigned)us2[0] | ((unsigned)us2[1] << 16);
  }
}

// ---------------- tokenizer (pure registers) ----------------
template<int KTX, int KTZ>
__device__ __forceinline__ void token_reg(
    const unsigned short* pk, int offX, const s16x8* afX,
    int offZ, const s16x8* afZ, const float* __restrict__ bx,
    int lane, unsigned xp[8][2], float d2o[4])
{
  const int r15 = lane & 15;
  const f32x4 z4 = {0.f,0.f,0.f,0.f};
  f32x4 acc[8];
  #pragma unroll
  for (int nt = 0; nt < 8; ++nt) acc[nt] = z4;
  #pragma unroll
  for (int kt = 0; kt < KTX; ++kt){
    #pragma unroll
    for (int nt = 0; nt < 8; ++nt)
      acc[nt] = MF(afX[kt], ldB(pk, offX + kt*8 + nt, lane), acc[nt]);
  }
  #pragma unroll
  for (int nt = 0; nt < 8; ++nt){
    float bv = bx[nt*16 + r15];
    float v0 = tanh_fast(acc[nt][0] + bv);
    float v1 = tanh_fast(acc[nt][1] + bv);
    float v2 = tanh_fast(acc[nt][2] + bv);
    float v3 = tanh_fast(acc[nt][3] + bv);
    xp[nt][0] = (unsigned)f2bf(v0) | ((unsigned)f2bf(v1) << 16);
    xp[nt][1] = (unsigned)f2bf(v2) | ((unsigned)f2bf(v3) << 16);
  }
  f32x4 a2[4];
  #pragma unroll
  for (int nt = 0; nt < 4; ++nt) a2[nt] = z4;
  #pragma unroll
  for (int kt = 0; kt < KTZ; ++kt){
    #pragma unroll
    for (int nt = 0; nt < 4; ++nt)
      a2[nt] = MF(afZ[kt], ldB(pk, offZ + kt*4 + nt, lane), a2[nt]);
  }
  #pragma unroll
  for (int j = 0; j < 4; ++j){
    float s = 0.f;
    #pragma unroll
    for (int nt = 0; nt < 4; ++nt){ float t = tanh_fast(a2[nt][j]); s += t*t; }
    d2o[j] = s;
  }
  #pragma unroll
  for (int m = 1; m < 16; m <<= 1){
    #pragma unroll
    for (int j = 0; j < 4; ++j) d2o[j] += __shfl_xor(d2o[j], m);
  }
}

// ---------------- main kernel (unchanged round 4) ----------------
__global__ __launch_bounds__(512, 2) void reward_main(
    const float* __restrict__ z, const float* __restrict__ action,
    const float* __restrict__ rw, const float* __restrict__ control,
    const float* __restrict__ act_bx, const float* __restrict__ ctl_bx,
    const float* __restrict__ cht_bx, const float* __restrict__ consb,
    const float* __restrict__ formb,
    const unsigned short* __restrict__ packed, const float* __restrict__ prep,
    const float* __restrict__ sig, float* __restrict__ out)
{
  __shared__ unsigned short pk_sh[65536];

  const int tid  = threadIdx.x;
  const int wid  = tid >> 6;
  const int lane = tid & 63;
  const int g0   = blockIdx.x*128 + wid*16;
  const int r15  = lane & 15;
  const int hi   = lane >> 4;
  const int ko   = hi << 3;
  const int arow = g0 + r15;
  const f32x4 z4 = {0.f,0.f,0.f,0.f};

  {
    uint4* d4 = reinterpret_cast<uint4*>(pk_sh);
    const uint4* s4 = reinterpret_cast<const uint4*>(packed);
    #pragma unroll
    for (int it = 0; it < 16; ++it)
      d4[it*512 + tid] = s4[it*512 + tid];
  }
  __syncthreads();
  const unsigned short* pk = pk_sh;

  s16x8 fz0 = ldA_g(z + (size_t)arow*64,            ko, 64);
  s16x8 fz1 = ldA_g(z + (size_t)arow*64 + 32,       ko, 32);
  s16x8 fac = ldA_g(action + (size_t)arow*32,       ko, 32);
  s16x8 fc0 = ldA_g(control + (size_t)arow*64,      ko, 64);
  s16x8 fc1 = ldA_g(control + (size_t)arow*64 + 32, ko, 32);
  s16x8 frw = ldA_g(rw + (size_t)arow*16,           ko, 16);

  unsigned xpk[3][8][2];
  float d2[3][4];
  {
    s16x8 afA[3] = {fac, fz0, fz1};
    token_reg<3,1>(pk, OFF_ACTX, afA, OFF_ACTZ, &fac, act_bx, lane, xpk[0], d2[0]);
  }
  {
    s16x8 afC[4] = {fc0, fc1, fz0, fz1};
    s16x8 afCz[2] = {fc0, fc1};
    token_reg<4,2>(pk, OFF_CTLX, afC, OFF_CTLZ, afCz, ctl_bx, lane, xpk[1], d2[1]);
  }
  {
    s16x8 afH[3] = {frw, fz0, fz1};
    token_reg<3,1>(pk, OFF_CHTX, afH, OFF_CHTZ, &frw, cht_bx, lane, xpk[2], d2[2]);
  }

  f32x4 qw[8];
  {
    #pragma unroll
    for (int nt = 0; nt < 8; ++nt) qw[nt] = z4;
    s16x8 afE[2] = {fz0, fz1};
    #pragma unroll
    for (int kt = 0; kt < 2; ++kt)
      #pragma unroll
      for (int nt = 0; nt < 8; ++nt)
        qw[nt] = MF(afE[kt], ldB(pk, OFF_WEQK + kt*8 + nt, lane), qw[nt]);
    const float* bqk = prep + 16384;
    #pragma unroll
    for (int nt = 0; nt < 8; ++nt){
      float bv = bqk[nt*16 + r15];
      #pragma unroll
      for (int j = 0; j < 4; ++j) qw[nt][j] += bv;
    }
  }

  f32x4 g[8];
  {
    #pragma unroll
    for (int nt = 0; nt < 8; ++nt) g[nt] = z4;
    s16x8 afG[2] = {fc0, fc1};
    #pragma unroll
    for (int kt = 0; kt < 2; ++kt)
      #pragma unroll
      for (int nt = 0; nt < 8; ++nt)
        g[nt] = MF(afG[kt], ldB(pk, OFF_WVOFT + kt*8 + nt, lane), g[nt]);
  }

  float sp[3][4];
  #pragma unroll
  for (int t = 0; t < 3; ++t){
    #pragma unroll
    for (int j = 0; j < 4; ++j) sp[t][j] = 0.f;
    #pragma unroll
    for (int nt = 0; nt < 8; ++nt){
      unsigned p0 = xpk[t][nt][0], p1 = xpk[t][nt][1];
      sp[t][0] += ubf_lo(p0)*qw[nt][0];
      sp[t][1] += ubf_hi(p0)*qw[nt][1];
      sp[t][2] += ubf_lo(p1)*qw[nt][2];
      sp[t][3] += ubf_hi(p1)*qw[nt][3];
    }
  }
  #pragma unroll
  for (int m = 1; m < 16; m <<= 1)
    #pragma unroll
    for (int t = 0; t < 3; ++t)
      #pragma unroll
      for (int j = 0; j < 4; ++j) sp[t][j] += __shfl_xor(sp[t][j], m);

  float at[3][4];
  #pragma unroll
  for (int j = 0; j < 4; ++j){
    const float isq = 0.0883883476483184f;
    float s0 = sp[0][j]*isq - d2[0][j];
    float s1 = sp[1][j]*isq - d2[1][j];
    float s2 = sp[2][j]*isq - d2[2][j];
    float mx = fmaxf(s0, fmaxf(s1, s2));
    float e0 = __expf(s0 - mx), e1 = __expf(s1 - mx), e2 = __expf(s2 - mx);
    float inv = 1.f/(e0 + e1 + e2);
    at[0][j] = e0*inv; at[1][j] = e1*inv; at[2][j] = e2*inv;
  }

  float xb[8][4];
  #pragma unroll
  for (int nt = 0; nt < 8; ++nt){
    #pragma unroll
    for (int j = 0; j < 4; ++j){
      unsigned p = xpk[0][nt][j>>1];
      float v = at[0][j] * ((j&1) ? ubf_hi(p) : ubf_lo(p));
      p = xpk[1][nt][j>>1];
      v += at[1][j] * ((j&1) ? ubf_hi(p) : ubf_lo(p));
      p = xpk[2][nt][j>>1];
      v += at[2][j] * ((j&1) ? ubf_hi(p) : ubf_lo(p));
      xb[nt][j] = v;
    }
  }

  const float inv_f = sig[0], inv_c = sig[1], cb = consb[0];
  const float* wvoc = prep + 16512;
  float wv[8];
  #pragma unroll
  for (int nt = 0; nt < 8; ++nt) wv[nt] = wvoc[nt*16 + r15];

  float tot[4];
  #pragma unroll
  for (int j = 0; j < 4; ++j){
    float sc = 0.f, sg = 0.f;
    #pragma unroll
    for (int nt = 0; nt < 8; ++nt){
      sc += xb[nt][j]*wv[nt];
      sg += xb[nt][j]*g[nt][j];
    }
    tot[j] = inv_c*sc + inv_f*sg;
  }
  #pragma unroll
  for (int m = 1; m < 16; m <<= 1)
    #pragma unroll
    for (int j = 0; j < 4; ++j) tot[j] += __shfl_xor(tot[j], m);

  float fbp = 0.f;
  {
    const float* cp = control + (size_t)arow*64;
    float4 c0a = *(const float4*)(cp + ko);
    float4 c0b = *(const float4*)(cp + ko + 4);
    float4 c1a = *(const float4*)(cp + 32 + ko);
    float4 c1b = *(const float4*)(cp + 32 + ko + 4);
    float4 f0a = *(const float4*)(formb + ko);
    float4 f0b = *(const float4*)(formb + ko + 4);
    float4 f1a = *(const float4*)(formb + 32 + ko);
    float4 f1b = *(const float4*)(formb + 32 + ko + 4);
    fbp = c0a.x*f0a.x + c0a.y*f0a.y + c0a.z*f0a.z + c0a.w*f0a.w
        + c0b.x*f0b.x + c0b.y*f0b.y + c0b.z*f0b.z + c0b.w*f0b.w
        + c1a.x*f1a.x + c1a.y*f1a.y + c1a.z*f1a.z + c1a.w*f1a.w
        + c1b.x*f1b.x + c1b.y*f1b.y + c1b.z*f1b.z + c1b.w*f1b.w;
  }
  fbp += __shfl_xor(fbp, 16);
  fbp += __shfl_xor(fbp, 32);

  float fbj[4];
  #pragma unroll
  for (int j = 0; j < 4; ++j) fbj[j] = __shfl(fbp, hi*4 + j);
  if (r15 == 0){
    #pragma unroll
    for (int j = 0; j < 4; ++j) out[g0 + hi*4 + j] = tot[j] + fbj[j] + cb;
  }
}

extern "C" void kernel_launch(void* const* d_in, const int* in_sizes, int n_in,
                              void* d_out, int out_size, void* d_ws, size_t ws_size,
                              hipStream_t stream)
{
  const float* z      = (const float*)d_in[0];
  const float* action = (const float*)d_in[1];
  const float* rw     = (const float*)d_in[2];
  const float* control= (const float*)d_in[3];
  const float* actWx  = (const float*)d_in[4];
  const float* actbx  = (const float*)d_in[5];
  const float* actWz  = (const float*)d_in[6];
  const float* ctlWx  = (const float*)d_in[7];
  const float* ctlbx  = (const float*)d_in[8];
  const float* ctlWz  = (const float*)d_in[9];
  const float* chtWx  = (const float*)d_in[10];
  const float* chtbx  = (const float*)d_in[11];
  const float* chtWz  = (const float*)d_in[12];
  const float* We     = (const float*)d_in[13];
  const float* be     = (const float*)d_in[14];
  const float* Wq     = (const float*)d_in[15];
  const float* Wk     = (const float*)d_in[16];
  const float* Wv     = (const float*)d_in[17];
  const float* Wo     = (const float*)d_in[18];
  const float* consW  = (const float*)d_in[19];
  const float* consb  = (const float*)d_in[20];
  const float* formW  = (const float*)d_in[21];
  const float* formb  = (const float*)d_in[22];
  float* out = (float*)d_out;

  unsigned short* packed = (unsigned short*)d_ws;
  float* sig  = (float*)((char*)d_ws + SIG_OFF);
  float* prep = (float*)((char*)d_ws + PREP_OFF);

  hipLaunchKernelGGL(prep_all, dim3(227), dim3(256), 0, stream,
                     We, be, Wq, Wk, Wv, Wo, consW, formW,
                     actWx, ctlWx, chtWx, actWz, ctlWz, chtWz,
                     packed, prep, sig);
  hipLaunchKernelGGL(reward_main, dim3(256), dim3(512), 0, stream,
                     z, action, rw, control, actbx, ctlbx, chtbx,
                     consb, formb, packed, prep, sig, out);
}

// Round 6
// 41.215 us; speedup vs baseline: 3.3606x; 1.0154x over previous
//
#include <hip/hip_runtime.h>
#include <hip/hip_bf16.h>

// RewardHead fused kernel for MI355X (gfx950) — round 6.
// B=32768, D=64, A=32, K=16, M=128. Output: [B,1] f32.
//
// vs round 5: fold blocks (prep_all b<130) stage the row-swept matrix
// (Wk/Wo/Wv) into LDS [128][129] via a coalesced linear copy, replacing the
// 64-way-uncoalesced global row reads (the ~27us hidden cost).
//
// d_ws: [0,128KB) packed bf16 B-fragments (128 tiles x 1KB)
//       [128KB,+8) sig; [128KB+256,...) prep f32: bqk@16384, wvoc@16512

typedef float f32x4 __attribute__((ext_vector_type(4)));
typedef short s16x8 __attribute__((ext_vector_type(8)));

#define OFF_ACTX  0
#define OFF_CTLX  24
#define OFF_CHTX  56
#define OFF_ACTZ  80
#define OFF_CTLZ  84
#define OFF_CHTZ  92
#define OFF_WEQK  96
#define OFF_WVOFT 112
#define N_TILES   128
#define SIG_OFF   (N_TILES*1024)
#define PREP_OFF  (SIG_OFF + 256)

__device__ __forceinline__ unsigned short f2bf(float f){
  unsigned u = __float_as_uint(f);
  u += 0x7fffu + ((u>>16)&1u);          // RNE
  return (unsigned short)(u>>16);
}
__device__ __forceinline__ float ubf_lo(unsigned u){ return __uint_as_float(u<<16); }
__device__ __forceinline__ float ubf_hi(unsigned u){ return __uint_as_float(u & 0xffff0000u); }

union V8 { s16x8 v; unsigned short us[8]; uint4 q; };

__device__ __forceinline__ f32x4 MF(s16x8 a, s16x8 b, f32x4 c){
  return __builtin_amdgcn_mfma_f32_16x16x32_bf16(a, b, c, 0, 0, 0);
}

__device__ __forceinline__ s16x8 ldB(const unsigned short* pk, int tile, int lane){
  V8 t;
  t.q = *reinterpret_cast<const uint4*>(pk + ((tile<<6) + lane)*8);
  return t.v;
}

__device__ __forceinline__ s16x8 ldA_g(const float* __restrict__ p, int ko, int limit){
  V8 t;
  if (ko < limit){
    const float4* q4 = reinterpret_cast<const float4*>(p + ko);
    float4 a = q4[0], b = q4[1];
    t.us[0]=f2bf(a.x); t.us[1]=f2bf(a.y); t.us[2]=f2bf(a.z); t.us[3]=f2bf(a.w);
    t.us[4]=f2bf(b.x); t.us[5]=f2bf(b.y); t.us[6]=f2bf(b.z); t.us[7]=f2bf(b.w);
  } else {
    t.q = make_uint4(0u,0u,0u,0u);
  }
  return t.v;
}

__device__ __forceinline__ float tanh_fast(float x){
  x = fminf(15.f, fmaxf(-15.f, x));
  float e = __expf(2.f*x);
  return 1.f - __fdividef(2.f, e + 1.f);
}

// ---------------- prep_all ----------------
__global__ __launch_bounds__(256) void prep_all(
    const float* __restrict__ We, const float* __restrict__ be,
    const float* __restrict__ Wq, const float* __restrict__ Wk,
    const float* __restrict__ Wv, const float* __restrict__ Wo,
    const float* __restrict__ consW, const float* __restrict__ formW,
    const float* __restrict__ aWx, const float* __restrict__ cWx,
    const float* __restrict__ hWx, const float* __restrict__ aWz,
    const float* __restrict__ cWz, const float* __restrict__ hWz,
    unsigned short* __restrict__ packed, float* __restrict__ prep,
    float* __restrict__ sig)
{
  const int b = blockIdx.x;
  const int tid = threadIdx.x;

  if (b < 130){
    // ---- fold rows. Row-swept matrices staged in LDS (coalesced);
    //      [129] padding => bank (tid+p)%32, 2 lanes/bank = conflict-free. ----
    __shared__ float Msh[128][129];
    __shared__ float tsh[128];
    if (b <= 64){
      // stage Wk (loop2 sweeps Wk rows)
      for (int idx = tid; idx < 16384; idx += 256)
        Msh[idx >> 7][idx & 127] = Wk[idx];
      // loop1 (coalesced): tsh = row @ Wq
      const float* rowv = (b == 64) ? be : (We + (size_t)b*128);
      if (tid < 128){
        float s = 0.f;
        for (int m = 0; m < 128; ++m) s += rowv[m]*Wq[(size_t)m*128 + tid];
        tsh[tid] = s;
      }
      __syncthreads();
      if (tid < 128){
        float s1 = 0.f;
        for (int p = 0; p < 128; ++p) s1 += tsh[p]*Msh[tid][p];
        if (b == 64) prep[16384 + tid] = s1;
        else {
          int r = b;
          int T = OFF_WEQK + ((r>>5)<<3) + (tid>>4);
          int l2 = (((r&31)>>3)<<4) | (tid&15);
          packed[((size_t)T*64 + l2)*8 + (r&7)] = f2bf(s1);
        }
      }
    } else {
      int d = b - 65;                        // 0..63: WvofT row d; 64: wvoc
      // stage Wo (loop1 sweeps Wo rows)
      for (int idx = tid; idx < 16384; idx += 256)
        Msh[idx >> 7][idx & 127] = Wo[idx];
      __syncthreads();
      if (tid < 128){
        float s = 0.f;
        if (d < 64){ for (int j = 0; j < 128; ++j) s += Msh[tid][j]*formW[(size_t)j*64 + d]; }
        else       { for (int j = 0; j < 128; ++j) s += Msh[tid][j]*consW[j]; }
        tsh[tid] = s;
      }
      __syncthreads();
      // stage Wv (loop2 sweeps Wv rows), reuse Msh
      for (int idx = tid; idx < 16384; idx += 256)
        Msh[idx >> 7][idx & 127] = Wv[idx];
      __syncthreads();
      if (tid < 128){
        float s1 = 0.f;
        for (int p = 0; p < 128; ++p) s1 += Msh[tid][p]*tsh[p];
        if (d < 64){
          int r = d;
          int T = OFF_WVOFT + ((r>>5)<<3) + (tid>>4);
          int l2 = (((r&31)>>3)<<4) | (tid&15);
          packed[((size_t)T*64 + l2)*8 + (r&7)] = f2bf(s1);
        } else prep[16512 + tid] = s1;
      }
    }
    return;
  }

  if (b == 130){
    // ---- spectral norms: 1-wave MFMA squaring chain ----
    __shared__ unsigned short SW[8192];   // W (128x64) in B-frag layout, 16 tiles
    __shared__ unsigned short SG[4096];   // G (64x64)  in B-frag layout, 8 tiles

    #pragma unroll
    for (int s4 = 0; s4 < 4; ++s4){
      int q = tid*4 + s4;                 // 0..1023
      int T = q >> 6, l = q & 63;
      V8 t;
      #pragma unroll
      for (int i = 0; i < 8; ++i){
        int k = (T>>2)*32 + ((l>>4)<<3) + i;
        int n = ((T&3)<<4) + (l&15);
        t.us[i] = f2bf(formW[(size_t)k*64 + n]);
      }
      *reinterpret_cast<uint4*>(&SW[q*8]) = t.q;
    }
    __syncthreads();
    if (tid >= 64) return;
    const int l = tid;
    const f32x4 z4 = {0.f,0.f,0.f,0.f};

    float cs;
    { float c0 = consW[l], c1 = consW[l+64];
      cs = c0*c0 + c1*c1;
      #pragma unroll
      for (int m = 1; m < 64; m <<= 1) cs += __shfl_xor(cs, m);
    }

    s16x8 wf[4][4];
    #pragma unroll
    for (int kt = 0; kt < 4; ++kt)
      #pragma unroll
      for (int x = 0; x < 4; ++x)
        wf[kt][x] = *reinterpret_cast<const s16x8*>(&SW[((((kt<<2)+x)<<6) | l)*8]);

    f32x4 D[4][4];
    #pragma unroll
    for (int it = 0; it < 4; ++it)
      #pragma unroll
      for (int nt = 0; nt < 4; ++nt){
        f32x4 a = z4;
        #pragma unroll
        for (int kt = 0; kt < 4; ++kt) a = MF(wf[kt][it], wf[kt][nt], a);
        D[it][nt] = a;
      }

    float L;
    {
      float ss = 0.f;
      #pragma unroll
      for (int it = 0; it < 4; ++it)
        #pragma unroll
        for (int nt = 0; nt < 4; ++nt)
          #pragma unroll
          for (int j = 0; j < 4; ++j) ss += D[it][nt][j]*D[it][nt][j];
      #pragma unroll
      for (int m = 1; m < 64; m <<= 1) ss += __shfl_xor(ss, m);
      float n0 = sqrtf(ss);
      L = logf(n0);
      float iv = 1.f/n0;
      #pragma unroll
      for (int it = 0; it < 4; ++it){
        int rb  = it*16 + ((l>>4)<<2);
        int lp  = (((rb&31)>>3)<<4) | (l&15);
        int ib  = rb & 7;
        int ktg = rb >> 5;
        #pragma unroll
        for (int nt = 0; nt < 4; ++nt){
          unsigned w0 = (unsigned)f2bf(D[it][nt][0]*iv) | ((unsigned)f2bf(D[it][nt][1]*iv)<<16);
          unsigned w1 = (unsigned)f2bf(D[it][nt][2]*iv) | ((unsigned)f2bf(D[it][nt][3]*iv)<<16);
          uint2 u; u.x = w0; u.y = w1;
          *reinterpret_cast<uint2*>(&SG[((((ktg<<2)+nt)<<6 | lp))*8 + ib]) = u;
        }
      }
    }

    for (int s = 1; s <= 6; ++s){
      s16x8 gf[2][4];
      #pragma unroll
      for (int kt = 0; kt < 2; ++kt)
        #pragma unroll
        for (int x = 0; x < 4; ++x)
          gf[kt][x] = *reinterpret_cast<const s16x8*>(&SG[((((kt<<2)+x)<<6) | l)*8]);
      f32x4 E[4][4];
      #pragma unroll
      for (int it = 0; it < 4; ++it)
        #pragma unroll
        for (int nt = 0; nt < 4; ++nt){
          f32x4 a = MF(gf[0][it], gf[0][nt], z4);
          E[it][nt] = MF(gf[1][it], gf[1][nt], a);
        }
      float ss = 0.f;
      #pragma unroll
      for (int it = 0; it < 4; ++it)
        #pragma unroll
        for (int nt = 0; nt < 4; ++nt)
          #pragma unroll
          for (int j = 0; j < 4; ++j) ss += E[it][nt][j]*E[it][nt][j];
      #pragma unroll
      for (int m = 1; m < 64; m <<= 1) ss += __shfl_xor(ss, m);
      float ns = sqrtf(ss);
      L = 2.f*L + logf(ns);
      if (s < 6){
        float iv = 1.f/ns;
        #pragma unroll
        for (int it = 0; it < 4; ++it){
          int rb  = it*16 + ((l>>4)<<2);
          int lp  = (((rb&31)>>3)<<4) | (l&15);
          int ib  = rb & 7;
          int ktg = rb >> 5;
          #pragma unroll
          for (int nt = 0; nt < 4; ++nt){
            unsigned w0 = (unsigned)f2bf(E[it][nt][0]*iv) | ((unsigned)f2bf(E[it][nt][1]*iv)<<16);
            unsigned w1 = (unsigned)f2bf(E[it][nt][2]*iv) | ((unsigned)f2bf(E[it][nt][3]*iv)<<16);
            uint2 u; u.x = w0; u.y = w1;
            *reinterpret_cast<uint2*>(&SG[((((ktg<<2)+nt)<<6 | lp))*8 + ib]) = u;
          }
        }
      }
    }

    if (l == 0){
      float sf = expf(L*(1.f/128.f));
      sig[0] = 1.f/(sf + 1e-6f);
      sig[1] = 1.f/(sqrtf(cs) + 1e-6f);
    }
    return;
  }

  // ---- blocks 131..226: pack tokenizer tiles 0..95 ----
  {
    int tile = b - 131;
    const float* W; int N; int kind = 0; int base;
    if      (tile < 24) { W=aWx; N=128; base=OFF_ACTX; }
    else if (tile < 56) { W=cWx; N=128; base=OFF_CTLX; }
    else if (tile < 80) { W=hWx; N=128; base=OFF_CHTX; kind=1; }
    else if (tile < 84) { W=aWz; N=64;  base=OFF_ACTZ; }
    else if (tile < 92) { W=cWz; N=64;  base=OFF_CTLZ; }
    else                { W=hWz; N=64;  base=OFF_CHTZ; kind=2; }
    int NT = N >> 4;
    int lt = tile - base;
    int nt = lt % NT, kt = lt / NT;
    int l = tid >> 2, i0 = (tid & 3)*2;
    unsigned short us2[2];
    #pragma unroll
    for (int di = 0; di < 2; ++di){
      int i = i0 + di;
      int k = kt*32 + ((l>>4)<<3) + i;
      int n = nt*16 + (l & 15);
      int sr = k;
      if (kind == 1) sr = (k < 16) ? k : (k < 32 ? -1 : k - 16);
      else if (kind == 2) sr = (k < 16) ? k : -1;
      float v = (sr >= 0) ? W[(size_t)sr*N + n] : 0.f;
      us2[di] = f2bf(v);
    }
    *reinterpret_cast<unsigned*>(&packed[((size_t)tile*64 + l)*8 + i0]) =
        (unsigned)us2[0] | ((unsigned)us2[1] << 16);
  }
}

// ---------------- tokenizer (pure registers) ----------------
template<int KTX, int KTZ>
__device__ __forceinline__ void token_reg(
    const unsigned short* pk, int offX, const s16x8* afX,
    int offZ, const s16x8* afZ, const float* __restrict__ bx,
    int lane, unsigned xp[8][2], float d2o[4])
{
  const int r15 = lane & 15;
  const f32x4 z4 = {0.f,0.f,0.f,0.f};
  f32x4 acc[8];
  #pragma unroll
  for (int nt = 0; nt < 8; ++nt) acc[nt] = z4;
  #pragma unroll
  for (int kt = 0; kt < KTX; ++kt){
    #pragma unroll
    for (int nt = 0; nt < 8; ++nt)
      acc[nt] = MF(afX[kt], ldB(pk, offX + kt*8 + nt, lane), acc[nt]);
  }
  #pragma unroll
  for (int nt = 0; nt < 8; ++nt){
    float bv = bx[nt*16 + r15];
    float v0 = tanh_fast(acc[nt][0] + bv);
    float v1 = tanh_fast(acc[nt][1] + bv);
    float v2 = tanh_fast(acc[nt][2] + bv);
    float v3 = tanh_fast(acc[nt][3] + bv);
    xp[nt][0] = (unsigned)f2bf(v0) | ((unsigned)f2bf(v1) << 16);
    xp[nt][1] = (unsigned)f2bf(v2) | ((unsigned)f2bf(v3) << 16);
  }
  f32x4 a2[4];
  #pragma unroll
  for (int nt = 0; nt < 4; ++nt) a2[nt] = z4;
  #pragma unroll
  for (int kt = 0; kt < KTZ; ++kt){
    #pragma unroll
    for (int nt = 0; nt < 4; ++nt)
      a2[nt] = MF(afZ[kt], ldB(pk, offZ + kt*4 + nt, lane), a2[nt]);
  }
  #pragma unroll
  for (int j = 0; j < 4; ++j){
    float s = 0.f;
    #pragma unroll
    for (int nt = 0; nt < 4; ++nt){ float t = tanh_fast(a2[nt][j]); s += t*t; }
    d2o[j] = s;
  }
  #pragma unroll
  for (int m = 1; m < 16; m <<= 1){
    #pragma unroll
    for (int j = 0; j < 4; ++j) d2o[j] += __shfl_xor(d2o[j], m);
  }
}

// ---------------- main kernel (unchanged) ----------------
__global__ __launch_bounds__(512, 2) void reward_main(
    const float* __restrict__ z, const float* __restrict__ action,
    const float* __restrict__ rw, const float* __restrict__ control,
    const float* __restrict__ act_bx, const float* __restrict__ ctl_bx,
    const float* __restrict__ cht_bx, const float* __restrict__ consb,
    const float* __restrict__ formb,
    const unsigned short* __restrict__ packed, const float* __restrict__ prep,
    const float* __restrict__ sig, float* __restrict__ out)
{
  __shared__ unsigned short pk_sh[65536];

  const int tid  = threadIdx.x;
  const int wid  = tid >> 6;
  const int lane = tid & 63;
  const int g0   = blockIdx.x*128 + wid*16;
  const int r15  = lane & 15;
  const int hi   = lane >> 4;
  const int ko   = hi << 3;
  const int arow = g0 + r15;
  const f32x4 z4 = {0.f,0.f,0.f,0.f};

  {
    uint4* d4 = reinterpret_cast<uint4*>(pk_sh);
    const uint4* s4 = reinterpret_cast<const uint4*>(packed);
    #pragma unroll
    for (int it = 0; it < 16; ++it)
      d4[it*512 + tid] = s4[it*512 + tid];
  }
  __syncthreads();
  const unsigned short* pk = pk_sh;

  s16x8 fz0 = ldA_g(z + (size_t)arow*64,            ko, 64);
  s16x8 fz1 = ldA_g(z + (size_t)arow*64 + 32,       ko, 32);
  s16x8 fac = ldA_g(action + (size_t)arow*32,       ko, 32);
  s16x8 fc0 = ldA_g(control + (size_t)arow*64,      ko, 64);
  s16x8 fc1 = ldA_g(control + (size_t)arow*64 + 32, ko, 32);
  s16x8 frw = ldA_g(rw + (size_t)arow*16,           ko, 16);

  unsigned xpk[3][8][2];
  float d2[3][4];
  {
    s16x8 afA[3] = {fac, fz0, fz1};
    token_reg<3,1>(pk, OFF_ACTX, afA, OFF_ACTZ, &fac, act_bx, lane, xpk[0], d2[0]);
  }
  {
    s16x8 afC[4] = {fc0, fc1, fz0, fz1};
    s16x8 afCz[2] = {fc0, fc1};
    token_reg<4,2>(pk, OFF_CTLX, afC, OFF_CTLZ, afCz, ctl_bx, lane, xpk[1], d2[1]);
  }
  {
    s16x8 afH[3] = {frw, fz0, fz1};
    token_reg<3,1>(pk, OFF_CHTX, afH, OFF_CHTZ, &frw, cht_bx, lane, xpk[2], d2[2]);
  }

  f32x4 qw[8];
  {
    #pragma unroll
    for (int nt = 0; nt < 8; ++nt) qw[nt] = z4;
    s16x8 afE[2] = {fz0, fz1};
    #pragma unroll
    for (int kt = 0; kt < 2; ++kt)
      #pragma unroll
      for (int nt = 0; nt < 8; ++nt)
        qw[nt] = MF(afE[kt], ldB(pk, OFF_WEQK + kt*8 + nt, lane), qw[nt]);
    const float* bqk = prep + 16384;
    #pragma unroll
    for (int nt = 0; nt < 8; ++nt){
      float bv = bqk[nt*16 + r15];
      #pragma unroll
      for (int j = 0; j < 4; ++j) qw[nt][j] += bv;
    }
  }

  f32x4 g[8];
  {
    #pragma unroll
    for (int nt = 0; nt < 8; ++nt) g[nt] = z4;
    s16x8 afG[2] = {fc0, fc1};
    #pragma unroll
    for (int kt = 0; kt < 2; ++kt)
      #pragma unroll
      for (int nt = 0; nt < 8; ++nt)
        g[nt] = MF(afG[kt], ldB(pk, OFF_WVOFT + kt*8 + nt, lane), g[nt]);
  }

  float sp[3][4];
  #pragma unroll
  for (int t = 0; t < 3; ++t){
    #pragma unroll
    for (int j = 0; j < 4; ++j) sp[t][j] = 0.f;
    #pragma unroll
    for (int nt = 0; nt < 8; ++nt){
      unsigned p0 = xpk[t][nt][0], p1 = xpk[t][nt][1];
      sp[t][0] += ubf_lo(p0)*qw[nt][0];
      sp[t][1] += ubf_hi(p0)*qw[nt][1];
      sp[t][2] += ubf_lo(p1)*qw[nt][2];
      sp[t][3] += ubf_hi(p1)*qw[nt][3];
    }
  }
  #pragma unroll
  for (int m = 1; m < 16; m <<= 1)
    #pragma unroll
    for (int t = 0; t < 3; ++t)
      #pragma unroll
      for (int j = 0; j < 4; ++j) sp[t][j] += __shfl_xor(sp[t][j], m);

  float at[3][4];
  #pragma unroll
  for (int j = 0; j < 4; ++j){
    const float isq = 0.0883883476483184f;
    float s0 = sp[0][j]*isq - d2[0][j];
    float s1 = sp[1][j]*isq - d2[1][j];
    float s2 = sp[2][j]*isq - d2[2][j];
    float mx = fmaxf(s0, fmaxf(s1, s2));
    float e0 = __expf(s0 - mx), e1 = __expf(s1 - mx), e2 = __expf(s2 - mx);
    float inv = 1.f/(e0 + e1 + e2);
    at[0][j] = e0*inv; at[1][j] = e1*inv; at[2][j] = e2*inv;
  }

  float xb[8][4];
  #pragma unroll
  for (int nt = 0; nt < 8; ++nt){
    #pragma unroll
    for (int j = 0; j < 4; ++j){
      unsigned p = xpk[0][nt][j>>1];
      float v = at[0][j] * ((j&1) ? ubf_hi(p) : ubf_lo(p));
      p = xpk[1][nt][j>>1];
      v += at[1][j] * ((j&1) ? ubf_hi(p) : ubf_lo(p));
      p = xpk[2][nt][j>>1];
      v += at[2][j] * ((j&1) ? ubf_hi(p) : ubf_lo(p));
      xb[nt][j] = v;
    }
  }

  const float inv_f = sig[0], inv_c = sig[1], cb = consb[0];
  const float* wvoc = prep + 16512;
  float wv[8];
  #pragma unroll
  for (int nt = 0; nt < 8; ++nt) wv[nt] = wvoc[nt*16 + r15];

  float tot[4];
  #pragma unroll
  for (int j = 0; j < 4; ++j){
    float sc = 0.f, sg = 0.f;
    #pragma unroll
    for (int nt = 0; nt < 8; ++nt){
      sc += xb[nt][j]*wv[nt];
      sg += xb[nt][j]*g[nt][j];
    }
    tot[j] = inv_c*sc + inv_f*sg;
  }
  #pragma unroll
  for (int m = 1; m < 16; m <<= 1)
    #pragma unroll
    for (int j = 0; j < 4; ++j) tot[j] += __shfl_xor(tot[j], m);

  float fbp = 0.f;
  {
    const float* cp = control + (size_t)arow*64;
    float4 c0a = *(const float4*)(cp + ko);
    float4 c0b = *(const float4*)(cp + ko + 4);
    float4 c1a = *(const float4*)(cp + 32 + ko);
    float4 c1b = *(const float4*)(cp + 32 + ko + 4);
    float4 f0a = *(const float4*)(formb + ko);
    float4 f0b = *(const float4*)(formb + ko + 4);
    float4 f1a = *(const float4*)(formb + 32 + ko);
    float4 f1b = *(const float4*)(formb + 32 + ko + 4);
    fbp = c0a.x*f0a.x + c0a.y*f0a.y + c0a.z*f0a.z + c0a.w*f0a.w
        + c0b.x*f0b.x + c0b.y*f0b.y + c0b.z*f0b.z + c0b.w*f0b.w
        + c1a.x*f1a.x + c1a.y*f1a.y + c1a.z*f1a.z + c1a.w*f1a.w
        + c1b.x*f1b.x + c1b.y*f1b.y + c1b.z*f1b.z + c1b.w*f1b.w;
  }
  fbp += __shfl_xor(fbp, 16);
  fbp += __shfl_xor(fbp, 32);

  float fbj[4];
  #pragma unroll
  for (int j = 0; j < 4; ++j) fbj[j] = __shfl(fbp, hi*4 + j);
  if (r15 == 0){
    #pragma unroll
    for (int j = 0; j < 4; ++j) out[g0 + hi*4 + j] = tot[j] + fbj[j] + cb;
  }
}

extern "C" void kernel_launch(void* const* d_in, const int* in_sizes, int n_in,
                              void* d_out, int out_size, void* d_ws, size_t ws_size,
                              hipStream_t stream)
{
  const float* z      = (const float*)d_in[0];
  const float* action = (const float*)d_in[1];
  const float* rw     = (const float*)d_in[2];
  const float* control= (const float*)d_in[3];
  const float* actWx  = (const float*)d_in[4];
  const float* actbx  = (const float*)d_in[5];
  const float* actWz  = (const float*)d_in[6];
  const float* ctlWx  = (const float*)d_in[7];
  const float* ctlbx  = (const float*)d_in[8];
  const float* ctlWz  = (const float*)d_in[9];
  const float* chtWx  = (const float*)d_in[10];
  const float* chtbx  = (const float*)d_in[11];
  const float* chtWz  = (const float*)d_in[12];
  const float* We     = (const float*)d_in[13];
  const float* be     = (const float*)d_in[14];
  const float* Wq     = (const float*)d_in[15];
  const float* Wk     = (const float*)d_in[16];
  const float* Wv     = (const float*)d_in[17];
  const float* Wo     = (const float*)d_in[18];
  const float* consW  = (const float*)d_in[19];
  const float* consb  = (const float*)d_in[20];
  const float* formW  = (const float*)d_in[21];
  const float* formb  = (const float*)d_in[22];
  float* out = (float*)d_out;

  unsigned short* packed = (unsigned short*)d_ws;
  float* sig  = (float*)((char*)d_ws + SIG_OFF);
  float* prep = (float*)((char*)d_ws + PREP_OFF);

  hipLaunchKernelGGL(prep_all, dim3(227), dim3(256), 0, stream,
                     We, be, Wq, Wk, Wv, Wo, consW, formW,
                     actWx, ctlWx, chtWx, actWz, ctlWz, chtWz,
                     packed, prep, sig);
  hipLaunchKernelGGL(reward_main, dim3(256), dim3(512), 0, stream,
                     z, action, rw, control, actbx, ctlbx, chtbx,
                     consb, formb, packed, prep, sig, out);
}